// Round 1
// baseline (877.568 us; speedup 1.0000x reference)
//
#include <hip/hip_runtime.h>

#define S_LEN 2048
#define DMODEL 4096
#define NH 32
#define NKV 8
#define DH 128
#define QDIM (NH*DH)     // 4096
#define KVDIM (NKV*DH)   // 1024
#define SCALE 0.08838834764831845f

typedef __attribute__((ext_vector_type(8))) short short8;
typedef __attribute__((ext_vector_type(4))) float f32x4;
typedef __attribute__((ext_vector_type(4))) unsigned short us4;

__device__ __forceinline__ unsigned short f2bf(float f) {
  union { float f; unsigned int u; } v; v.f = f;
  unsigned int r = v.u + 0x7FFFu + ((v.u >> 16) & 1u);
  return (unsigned short)(r >> 16);
}
__device__ __forceinline__ float bf2f(unsigned short h) {
  union { unsigned int u; float f; } v; v.u = ((unsigned int)h) << 16;
  return v.f;
}

// ---------------- f32 -> bf16 convert (4 elems/thread) ----------------
__global__ __launch_bounds__(256) void cvt_bf16(const float* __restrict__ in,
                                                unsigned short* __restrict__ out, int n4) {
  int i = blockIdx.x * 256 + threadIdx.x;
  if (i >= n4) return;
  const float4 f = reinterpret_cast<const float4*>(in)[i];
  us4 o;
  o.x = f2bf(f.x); o.y = f2bf(f.y); o.z = f2bf(f.z); o.w = f2bf(f.w);
  reinterpret_cast<us4*>(out)[i] = o;
}

// ---------------- GEMM: C[M,N] = A[M,K] * B[N,K]^T  (m97-style 128x128) ----------------
template<int OUT_BF16>
__global__ __launch_bounds__(256) void gemm_bt(const unsigned short* __restrict__ A,
                                               const unsigned short* __restrict__ B,
                                               void* __restrict__ Cv,
                                               int M, int N, int K) {
  __shared__ unsigned short lds[8192]; // A tile [128][32] @0, B tile [128][32] @4096
  const int tid = threadIdx.x;
  const int lane = tid & 63;
  const int wave = tid >> 6;
  const int wr = wave >> 1, wc = wave & 1;
  const int fr = lane & 15, fq = lane >> 4;
  const long m0 = (long)blockIdx.y * 128;
  const long n0 = (long)blockIdx.x * 128;
  const int srow = tid >> 2;
  const int scol = (tid & 3) * 8;

  f32x4 acc[4][4] = {};

  for (int k0 = 0; k0 < K; k0 += 32) {
#pragma unroll
    for (int i = 0; i < 2; ++i) {
      __builtin_amdgcn_global_load_lds(
          (const __attribute__((address_space(1))) void*)(A + (m0 + i*64 + srow) * (long)K + k0 + scol),
          (__attribute__((address_space(3))) void*)((char*)lds + i*4096 + tid*16),
          16, 0, 0);
      __builtin_amdgcn_global_load_lds(
          (const __attribute__((address_space(1))) void*)(B + (n0 + i*64 + srow) * (long)K + k0 + scol),
          (__attribute__((address_space(3))) void*)((char*)lds + 8192 + i*4096 + tid*16),
          16, 0, 0);
    }
    __syncthreads();

    short8 a[4], b[4];
#pragma unroll
    for (int m = 0; m < 4; ++m)
      a[m] = *reinterpret_cast<const short8*>(lds + (wr*64 + m*16 + fr)*32 + fq*8);
#pragma unroll
    for (int n = 0; n < 4; ++n)
      b[n] = *reinterpret_cast<const short8*>(lds + 4096 + (wc*64 + n*16 + fr)*32 + fq*8);
#pragma unroll
    for (int m = 0; m < 4; ++m)
#pragma unroll
      for (int n = 0; n < 4; ++n)
        acc[m][n] = __builtin_amdgcn_mfma_f32_16x16x32_bf16(a[m], b[n], acc[m][n], 0, 0, 0);
    __syncthreads();
  }

#pragma unroll
  for (int m = 0; m < 4; ++m) {
#pragma unroll
    for (int n = 0; n < 4; ++n) {
#pragma unroll
      for (int j = 0; j < 4; ++j) {
        long r = m0 + wr*64 + m*16 + fq*4 + j;
        long c = n0 + wc*64 + n*16 + fr;
        float v = acc[m][n][j];
        if (OUT_BF16) ((unsigned short*)Cv)[r * (long)N + c] = f2bf(v);
        else          ((float*)Cv)[r * (long)N + c] = v;
      }
    }
  }
}

// ---------------- YaRN RoPE in-place on bf16 (pair i, i+64 per thread) ----------------
__global__ __launch_bounds__(256) void rope_inplace(unsigned short* __restrict__ X,
                                                    const float* __restrict__ cosb,
                                                    const float* __restrict__ sinb,
                                                    int nH) {
  int idx = blockIdx.x * 256 + threadIdx.x;
  int i = idx & 63;
  int t = idx >> 6;       // s*nH + h
  int hh = t % nH;
  int s = t / nH;
  unsigned short* row = X + (size_t)s * ((size_t)nH * DH) + (size_t)hh * DH;
  float c  = cosb[s * DH + i];
  float sn = sinb[s * DH + i];
  float x1 = bf2f(row[i]);
  float x2 = bf2f(row[i + 64]);
  row[i]      = f2bf(x1 * c - x2 * sn);
  row[i + 64] = f2bf(x2 * c + x1 * sn);
}

// ---------------- GQA causal flash attention ----------------
// grid: (S/64, H). 4 waves/block, wave w owns q rows [qb + 16w, qb + 16w + 16).
__global__ __launch_bounds__(256) void attn_fwd(const unsigned short* __restrict__ Qb,
                                                const unsigned short* __restrict__ Kb,
                                                const unsigned short* __restrict__ Vb,
                                                unsigned short* __restrict__ Ob) {
  __shared__ unsigned short Klds[32 * 136];   // [kv][136], cols 0..127 valid (pad kills 16-way conflict)
  __shared__ unsigned short Vt[128 * 40];     // [d][40], cols 0..31 valid (stride 80B: 16B-aligned reads)
  __shared__ unsigned short Plds[4][16 * 40]; // per wave: [q][40], cols 0..31 valid
  const int tid = threadIdx.x;
  const int lane = tid & 63;
  const int wave = tid >> 6;
  const int h = blockIdx.y;
  const int kvh = h >> 2;
  const int qb = blockIdx.x * 64;
  const int q0 = qb + wave * 16;
  const int fr = lane & 15, fq = lane >> 4;

  // Q fragments: wave's 16 rows x 128 d (loaded once from global)
  short8 qf[4];
#pragma unroll
  for (int dc = 0; dc < 4; ++dc)
    qf[dc] = *reinterpret_cast<const short8*>(
        Qb + (size_t)(q0 + fr) * QDIM + h * DH + dc * 32 + fq * 8);

  f32x4 o_acc[8] = {};
  float mrow[4] = {-1e30f, -1e30f, -1e30f, -1e30f};
  float lrow[4] = {0.f, 0.f, 0.f, 0.f};

  const int kv_end = qb + 64;
  for (int kv0 = 0; kv0 < kv_end; kv0 += 32) {
    __syncthreads();  // prior iteration's LDS reads done before overwrite
    // stage K [32][128] -> Klds, V -> Vt (transposed)
#pragma unroll
    for (int it = 0; it < 2; ++it) {
      int e = it * 2048 + tid * 8;
      int r = e >> 7, c = e & 127;
      *reinterpret_cast<short8*>(Klds + r * 136 + c) =
          *reinterpret_cast<const short8*>(Kb + (size_t)(kv0 + r) * KVDIM + kvh * DH + c);
      short8 v = *reinterpret_cast<const short8*>(Vb + (size_t)(kv0 + r) * KVDIM + kvh * DH + c);
#pragma unroll
      for (int j = 0; j < 8; ++j) Vt[(c + j) * 40 + r] = ((unsigned short*)&v)[j];
    }
    __syncthreads();

    if (kv0 < q0 + 16) {
      // scores: S[16q][32kv] via 2 n-tiles x 4 d-chunks
      f32x4 sacc[2] = {};
#pragma unroll
      for (int nt = 0; nt < 2; ++nt)
#pragma unroll
        for (int dc = 0; dc < 4; ++dc) {
          short8 kf = *reinterpret_cast<const short8*>(Klds + (nt*16 + fr)*136 + dc*32 + fq*8);
          sacc[nt] = __builtin_amdgcn_mfma_f32_16x16x32_bf16(qf[dc], kf, sacc[nt], 0, 0, 0);
        }

      float pv[2][4];
      float tmax[4];
#pragma unroll
      for (int j = 0; j < 4; ++j) {
        int qrow = q0 + fq * 4 + j;
        float v0 = sacc[0][j] * SCALE;
        float v1 = sacc[1][j] * SCALE;
        v0 = ((kv0 + fr)      <= qrow) ? v0 : -1e30f;
        v1 = ((kv0 + 16 + fr) <= qrow) ? v1 : -1e30f;
        pv[0][j] = v0; pv[1][j] = v1;
        float t = fmaxf(v0, v1);
        t = fmaxf(t, __shfl_xor(t, 1));
        t = fmaxf(t, __shfl_xor(t, 2));
        t = fmaxf(t, __shfl_xor(t, 4));
        t = fmaxf(t, __shfl_xor(t, 8));
        tmax[j] = t;
      }
#pragma unroll
      for (int j = 0; j < 4; ++j) {
        float mnew = fmaxf(mrow[j], tmax[j]);
        float corr = __expf(mrow[j] - mnew);
        float p0 = __expf(pv[0][j] - mnew);   // masked -> exp(-1e30) = 0
        float p1 = __expf(pv[1][j] - mnew);
        float rs = p0 + p1;
        rs += __shfl_xor(rs, 1);
        rs += __shfl_xor(rs, 2);
        rs += __shfl_xor(rs, 4);
        rs += __shfl_xor(rs, 8);
        lrow[j] = lrow[j] * corr + rs;
        mrow[j] = mnew;
#pragma unroll
        for (int dt = 0; dt < 8; ++dt) o_acc[dt][j] *= corr;
        Plds[wave][(fq*4 + j)*40 + fr]      = f2bf(p0);
        Plds[wave][(fq*4 + j)*40 + 16 + fr] = f2bf(p1);
      }
      asm volatile("s_waitcnt lgkmcnt(0)" ::: "memory");
      // PV: A = P[16q][32kv], B = V[32kv][16d] per d-tile
      short8 pa = *reinterpret_cast<const short8*>(&Plds[wave][fr*40 + fq*8]);
#pragma unroll
      for (int dt = 0; dt < 8; ++dt) {
        short8 bv = *reinterpret_cast<const short8*>(Vt + (dt*16 + fr)*40 + fq*8);
        o_acc[dt] = __builtin_amdgcn_mfma_f32_16x16x32_bf16(pa, bv, o_acc[dt], 0, 0, 0);
      }
    }
  }

#pragma unroll
  for (int dt = 0; dt < 8; ++dt)
#pragma unroll
    for (int j = 0; j < 4; ++j) {
      size_t r = (size_t)q0 + fq*4 + j;
      Ob[r * QDIM + h * DH + dt*16 + fr] = f2bf(o_acc[dt][j] / lrow[j]);
    }
}

// ---------------- launch ----------------
extern "C" void kernel_launch(void* const* d_in, const int* in_sizes, int n_in,
                              void* d_out, int out_size, void* d_ws, size_t ws_size,
                              hipStream_t stream) {
  (void)in_sizes; (void)n_in; (void)out_size; (void)ws_size;
  const float* x    = (const float*)d_in[0];
  const float* Wq   = (const float*)d_in[1];
  const float* Wk   = (const float*)d_in[2];
  const float* Wv   = (const float*)d_in[3];
  const float* Wo   = (const float*)d_in[4];
  const float* cosb = (const float*)d_in[5];
  const float* sinb = (const float*)d_in[6];

  char* ws = (char*)d_ws;
  unsigned short* xb   = (unsigned short*)(ws);               // 16.8 MB
  unsigned short* Wqb  = (unsigned short*)(ws + 16777216);    // 33.5 MB
  unsigned short* Wkb  = (unsigned short*)(ws + 50331648);    // 8.4 MB
  unsigned short* Wvb  = (unsigned short*)(ws + 58720256);    // 8.4 MB
  unsigned short* Wob  = (unsigned short*)(ws + 67108864);    // 33.5 MB
  unsigned short* Qb   = (unsigned short*)(ws + 100663296);   // 16.8 MB
  unsigned short* Kbuf = (unsigned short*)(ws + 117440512);   // 4.2 MB
  unsigned short* Vbuf = (unsigned short*)(ws + 121634816);   // 4.2 MB
  unsigned short* Ab   = (unsigned short*)(ws + 125829120);   // 16.8 MB  (total 142.6 MB)

  cvt_bf16<<<8388608/1024, 256, 0, stream>>>(x,  xb,  8388608/4);
  cvt_bf16<<<16777216/1024, 256, 0, stream>>>(Wq, Wqb, 16777216/4);
  cvt_bf16<<<4194304/1024, 256, 0, stream>>>(Wk, Wkb, 4194304/4);
  cvt_bf16<<<4194304/1024, 256, 0, stream>>>(Wv, Wvb, 4194304/4);
  cvt_bf16<<<16777216/1024, 256, 0, stream>>>(Wo, Wob, 16777216/4);

  gemm_bt<1><<<dim3(32, 16), 256, 0, stream>>>(xb, Wqb, Qb,   2048, 4096, 4096);
  gemm_bt<1><<<dim3(8, 16),  256, 0, stream>>>(xb, Wkb, Kbuf, 2048, 1024, 4096);
  gemm_bt<1><<<dim3(8, 16),  256, 0, stream>>>(xb, Wvb, Vbuf, 2048, 1024, 4096);

  rope_inplace<<<16384, 256, 0, stream>>>(Qb,   cosb, sinb, NH);
  rope_inplace<<<4096,  256, 0, stream>>>(Kbuf, cosb, sinb, NKV);

  attn_fwd<<<dim3(32, 32), 256, 0, stream>>>(Qb, Kbuf, Vbuf, Ab);

  gemm_bt<0><<<dim3(32, 16), 256, 0, stream>>>(Ab, Wob, d_out, 2048, 4096, 4096);
}

// Round 2
// 689.267 us; speedup vs baseline: 1.2732x; 1.2732x over previous
//
#include <hip/hip_runtime.h>

#define S_LEN 2048
#define DMODEL 4096
#define NH 32
#define NKV 8
#define DH 128
#define QDIM (NH*DH)     // 4096
#define KVDIM (NKV*DH)   // 1024
#define SCALE 0.08838834764831845f

typedef __attribute__((ext_vector_type(8))) short short8;
typedef __attribute__((ext_vector_type(4))) float f32x4;
typedef __attribute__((ext_vector_type(4))) unsigned short us4;

__device__ __forceinline__ unsigned short f2bf(float f) {
  union { float f; unsigned int u; } v; v.f = f;
  unsigned int r = v.u + 0x7FFFu + ((v.u >> 16) & 1u);
  return (unsigned short)(r >> 16);
}
__device__ __forceinline__ float bf2f(unsigned short h) {
  union { unsigned int u; float f; } v; v.u = ((unsigned int)h) << 16;
  return v.f;
}

// ---------------- f32 -> bf16 convert (4 elems/thread) ----------------
__global__ __launch_bounds__(256) void cvt_bf16(const float* __restrict__ in,
                                                unsigned short* __restrict__ out, int n4) {
  int i = blockIdx.x * 256 + threadIdx.x;
  if (i >= n4) return;
  const float4 f = reinterpret_cast<const float4*>(in)[i];
  us4 o;
  o.x = f2bf(f.x); o.y = f2bf(f.y); o.z = f2bf(f.z); o.w = f2bf(f.w);
  reinterpret_cast<us4*>(out)[i] = o;
}

// ---------------- GEMM: C[M,N] = A[M,K] * B[N,K]^T  (m97-style 128x128) ----------------
template<int OUT_BF16>
__global__ __launch_bounds__(256) void gemm_bt(const unsigned short* __restrict__ A,
                                               const unsigned short* __restrict__ B,
                                               void* __restrict__ Cv,
                                               int M, int N, int K) {
  __shared__ unsigned short lds[8192]; // A tile [128][32] @0, B tile [128][32] @4096
  const int tid = threadIdx.x;
  const int lane = tid & 63;
  const int wave = tid >> 6;
  const int wr = wave >> 1, wc = wave & 1;
  const int fr = lane & 15, fq = lane >> 4;
  const long m0 = (long)blockIdx.y * 128;
  const long n0 = (long)blockIdx.x * 128;
  const int srow = tid >> 2;
  const int scol = (tid & 3) * 8;

  f32x4 acc[4][4] = {};

  for (int k0 = 0; k0 < K; k0 += 32) {
#pragma unroll
    for (int i = 0; i < 2; ++i) {
      __builtin_amdgcn_global_load_lds(
          (const __attribute__((address_space(1))) void*)(A + (m0 + i*64 + srow) * (long)K + k0 + scol),
          (__attribute__((address_space(3))) void*)((char*)lds + i*4096 + tid*16),
          16, 0, 0);
      __builtin_amdgcn_global_load_lds(
          (const __attribute__((address_space(1))) void*)(B + (n0 + i*64 + srow) * (long)K + k0 + scol),
          (__attribute__((address_space(3))) void*)((char*)lds + 8192 + i*4096 + tid*16),
          16, 0, 0);
    }
    __syncthreads();

    short8 a[4], b[4];
#pragma unroll
    for (int m = 0; m < 4; ++m)
      a[m] = *reinterpret_cast<const short8*>(lds + (wr*64 + m*16 + fr)*32 + fq*8);
#pragma unroll
    for (int n = 0; n < 4; ++n)
      b[n] = *reinterpret_cast<const short8*>(lds + 4096 + (wc*64 + n*16 + fr)*32 + fq*8);
#pragma unroll
    for (int m = 0; m < 4; ++m)
#pragma unroll
      for (int n = 0; n < 4; ++n)
        acc[m][n] = __builtin_amdgcn_mfma_f32_16x16x32_bf16(a[m], b[n], acc[m][n], 0, 0, 0);
    __syncthreads();
  }

#pragma unroll
  for (int m = 0; m < 4; ++m) {
#pragma unroll
    for (int n = 0; n < 4; ++n) {
#pragma unroll
      for (int j = 0; j < 4; ++j) {
        long r = m0 + wr*64 + m*16 + fq*4 + j;
        long c = n0 + wc*64 + n*16 + fr;
        float v = acc[m][n][j];
        if (OUT_BF16) ((unsigned short*)Cv)[r * (long)N + c] = f2bf(v);
        else          ((float*)Cv)[r * (long)N + c] = v;
      }
    }
  }
}

// ---------------- YaRN RoPE in-place on bf16 (pair i, i+64 per thread) ----------------
__global__ __launch_bounds__(256) void rope_inplace(unsigned short* __restrict__ X,
                                                    const float* __restrict__ cosb,
                                                    const float* __restrict__ sinb,
                                                    int nH) {
  int idx = blockIdx.x * 256 + threadIdx.x;
  int i = idx & 63;
  int t = idx >> 6;       // s*nH + h
  int hh = t % nH;
  int s = t / nH;
  unsigned short* row = X + (size_t)s * ((size_t)nH * DH) + (size_t)hh * DH;
  float c  = cosb[s * DH + i];
  float sn = sinb[s * DH + i];
  float x1 = bf2f(row[i]);
  float x2 = bf2f(row[i + 64]);
  row[i]      = f2bf(x1 * c - x2 * sn);
  row[i + 64] = f2bf(x2 * c + x1 * sn);
}

// ---------------- V transpose: Vbuf[s][1024] -> VT[kvh][d][s] ----------------
__global__ __launch_bounds__(256) void transpose_v(const unsigned short* __restrict__ Vbuf,
                                                   unsigned short* __restrict__ VT) {
  __shared__ unsigned short t[64][72];
  const int s0 = blockIdx.x * 64, e0 = blockIdx.y * 64;
  const int r = threadIdx.x >> 3, c = (threadIdx.x & 7) * 8;
#pragma unroll
  for (int half = 0; half < 2; ++half) {
    int row = r + half * 32;
    *reinterpret_cast<short8*>(&t[row][c]) =
        *reinterpret_cast<const short8*>(Vbuf + (size_t)(s0 + row) * KVDIM + e0 + c);
  }
  __syncthreads();
  const int hh = e0 >> 7, dbase = e0 & 127;
#pragma unroll
  for (int half = 0; half < 2; ++half) {
    int row = r + half * 32;   // d offset within the 64-col slab
    short8 o;
#pragma unroll
    for (int j = 0; j < 8; ++j) ((unsigned short*)&o)[j] = t[c + j][row];
    *reinterpret_cast<short8*>(VT + (size_t)hh * (DH * (size_t)S_LEN)
                               + (size_t)(dbase + row) * S_LEN + s0 + c) = o;
  }
}

// ---------------- GQA causal flash attention ----------------
// grid: (S/128, H). 4 waves/block; wave w owns q rows [qb + 32w, qb + 32w + 32). KVBLK=64.
__global__ __launch_bounds__(256) void attn_fwd(const unsigned short* __restrict__ Qb,
                                                const unsigned short* __restrict__ Kb,
                                                const unsigned short* __restrict__ VT,
                                                unsigned short* __restrict__ Ob) {
  __shared__ unsigned short Kl[64 * 128];     // swizzled-linear: byte b holds K[b>>8][((b&255)^((row&7)<<4))/2]
  __shared__ unsigned short Vl[128 * 64];     // swizzled-linear: byte b holds VT[b>>7][((b&127)^((row&7)<<4))/2]
  __shared__ unsigned short Pl[4][32 * 72];   // per-wave P [32 q][72], cols 0..63 valid
  const int tid = threadIdx.x;
  const int lane = tid & 63;
  const int wave = tid >> 6;
  const int h = blockIdx.y;
  const int kvh = h >> 2;
  const int qbi = (gridDim.x - 1) - blockIdx.x;   // heaviest causal blocks dispatch first
  const int qb = qbi * 128;
  const int q0 = qb + wave * 32;
  const int fr = lane & 15, fq = lane >> 4;

  // Q fragments: wave's 32 rows x 128 d
  short8 qf[2][4];
#pragma unroll
  for (int m = 0; m < 2; ++m)
#pragma unroll
    for (int dc = 0; dc < 4; ++dc)
      qf[m][dc] = *reinterpret_cast<const short8*>(
          Qb + (size_t)(q0 + m*16 + fr) * QDIM + h * DH + dc * 32 + fq * 8);

  f32x4 o_acc[2][8] = {};
  float mrow[2][4] = {{-1e30f,-1e30f,-1e30f,-1e30f},{-1e30f,-1e30f,-1e30f,-1e30f}};
  float lpart[2][4] = {};

  const unsigned short* Kbase = Kb + (size_t)kvh * DH;
  const unsigned short* Vbase = VT + (size_t)kvh * (DH * (size_t)S_LEN);

  const int kv_end = qb + 128;
  for (int kv0 = 0; kv0 < kv_end; kv0 += 64) {
    __syncthreads();   // prior iteration's LDS reads done before overwrite
    // stage K[64][128] and V^T[128][64] via global_load_lds, pre-swizzled source (m173)
#pragma unroll
    for (int sh = 0; sh < 4; ++sh) {
      int b = sh * 4096 + tid * 16;
      int krow = b >> 8;
      int kcol = (b & 255) ^ ((krow & 7) << 4);
      __builtin_amdgcn_global_load_lds(
          (const __attribute__((address_space(1))) void*)(Kbase + (size_t)(kv0 + krow) * KVDIM + (kcol >> 1)),
          (__attribute__((address_space(3))) void*)((char*)Kl + b), 16, 0, 0);
      int vrow = b >> 7;
      int vcol = (b & 127) ^ ((vrow & 7) << 4);
      __builtin_amdgcn_global_load_lds(
          (const __attribute__((address_space(1))) void*)(Vbase + (size_t)vrow * S_LEN + kv0 + (vcol >> 1)),
          (__attribute__((address_space(3))) void*)((char*)Vl + b), 16, 0, 0);
    }
    __syncthreads();

    if (kv0 < q0 + 32) {
      const bool needMask = (kv0 + 64 > q0);
      // ---- QK^T: S[32 q][64 kv] ----
      f32x4 sacc[2][4] = {};
#pragma unroll
      for (int nt = 0; nt < 4; ++nt) {
#pragma unroll
        for (int dc = 0; dc < 4; ++dc) {
          int row = nt * 16 + fr;
          short8 kf = *reinterpret_cast<const short8*>(
              (const char*)Kl + row * 256 + ((dc * 64 + fq * 16) ^ ((row & 7) << 4)));
          sacc[0][nt] = __builtin_amdgcn_mfma_f32_16x16x32_bf16(qf[0][dc], kf, sacc[0][nt], 0, 0, 0);
          sacc[1][nt] = __builtin_amdgcn_mfma_f32_16x16x32_bf16(qf[1][dc], kf, sacc[1][nt], 0, 0, 0);
        }
      }
      // ---- online softmax (defer-max, per-lane partial sums) ----
#pragma unroll
      for (int m = 0; m < 2; ++m) {
        float tm[4];
#pragma unroll
        for (int j = 0; j < 4; ++j) {
          if (needMask) {
            int qrow = q0 + m*16 + fq*4 + j;
#pragma unroll
            for (int nt = 0; nt < 4; ++nt) {
              float v = sacc[m][nt][j] * SCALE;
              sacc[m][nt][j] = ((kv0 + nt*16 + fr) <= qrow) ? v : -1e30f;
            }
          } else {
#pragma unroll
            for (int nt = 0; nt < 4; ++nt) sacc[m][nt][j] *= SCALE;
          }
          float t = fmaxf(fmaxf(sacc[m][0][j], sacc[m][1][j]),
                          fmaxf(sacc[m][2][j], sacc[m][3][j]));
          t = fmaxf(t, __shfl_xor(t, 1));
          t = fmaxf(t, __shfl_xor(t, 2));
          t = fmaxf(t, __shfl_xor(t, 4));
          t = fmaxf(t, __shfl_xor(t, 8));
          tm[j] = t;
        }
        bool noResc = (tm[0] <= mrow[m][0] + 8.f) && (tm[1] <= mrow[m][1] + 8.f)
                   && (tm[2] <= mrow[m][2] + 8.f) && (tm[3] <= mrow[m][3] + 8.f);
        if (!__all(noResc)) {
#pragma unroll
          for (int j = 0; j < 4; ++j) {
            float mnew = fmaxf(mrow[m][j], tm[j]);
            float corr = __expf(mrow[m][j] - mnew);
            mrow[m][j] = mnew;
            lpart[m][j] *= corr;
#pragma unroll
            for (int dt = 0; dt < 8; ++dt) o_acc[m][dt][j] *= corr;
          }
        }
#pragma unroll
        for (int j = 0; j < 4; ++j) {
          float msub = mrow[m][j];
          float ls = 0.f;
#pragma unroll
          for (int nt = 0; nt < 4; ++nt) {
            float p = __expf(sacc[m][nt][j] - msub);   // masked -> exp(-1e30-..) = 0
            ls += p;
            Pl[wave][(m*16 + fq*4 + j)*72 + nt*16 + fr] = f2bf(p);
          }
          lpart[m][j] += ls;
        }
      }
      asm volatile("s_waitcnt lgkmcnt(0)" ::: "memory");
      __builtin_amdgcn_sched_barrier(0);
      // ---- PV: O += P[32 q][64 kv] * V[64 kv][128 d] ----
#pragma unroll
      for (int ks = 0; ks < 2; ++ks) {
        short8 pa0 = *reinterpret_cast<const short8*>(&Pl[wave][(fr)*72      + ks*32 + fq*8]);
        short8 pa1 = *reinterpret_cast<const short8*>(&Pl[wave][(16+fr)*72   + ks*32 + fq*8]);
#pragma unroll
        for (int dt = 0; dt < 8; ++dt) {
          int row = dt * 16 + fr;
          short8 bv = *reinterpret_cast<const short8*>(
              (const char*)Vl + row * 128 + ((ks * 64 + fq * 16) ^ ((row & 7) << 4)));
          o_acc[0][dt] = __builtin_amdgcn_mfma_f32_16x16x32_bf16(pa0, bv, o_acc[0][dt], 0, 0, 0);
          o_acc[1][dt] = __builtin_amdgcn_mfma_f32_16x16x32_bf16(pa1, bv, o_acc[1][dt], 0, 0, 0);
        }
      }
    }
  }

  // epilogue: reduce row sums across fr lanes, normalize, store
#pragma unroll
  for (int m = 0; m < 2; ++m)
#pragma unroll
    for (int j = 0; j < 4; ++j) {
      float l = lpart[m][j];
      l += __shfl_xor(l, 1);
      l += __shfl_xor(l, 2);
      l += __shfl_xor(l, 4);
      l += __shfl_xor(l, 8);
      float inv = 1.f / l;
      size_t r = (size_t)q0 + m*16 + fq*4 + j;
#pragma unroll
      for (int dt = 0; dt < 8; ++dt)
        Ob[r * QDIM + h * DH + dt*16 + fr] = f2bf(o_acc[m][dt][j] * inv);
    }
}

// ---------------- launch ----------------
extern "C" void kernel_launch(void* const* d_in, const int* in_sizes, int n_in,
                              void* d_out, int out_size, void* d_ws, size_t ws_size,
                              hipStream_t stream) {
  (void)in_sizes; (void)n_in; (void)out_size; (void)ws_size;
  const float* x    = (const float*)d_in[0];
  const float* Wq   = (const float*)d_in[1];
  const float* Wk   = (const float*)d_in[2];
  const float* Wv   = (const float*)d_in[3];
  const float* Wo   = (const float*)d_in[4];
  const float* cosb = (const float*)d_in[5];
  const float* sinb = (const float*)d_in[6];

  char* ws = (char*)d_ws;
  unsigned short* xb   = (unsigned short*)(ws);               // 16.8 MB
  unsigned short* Wqb  = (unsigned short*)(ws + 16777216);    // 33.5 MB
  unsigned short* Wkb  = (unsigned short*)(ws + 50331648);    // 8.4 MB
  unsigned short* Wvb  = (unsigned short*)(ws + 58720256);    // 8.4 MB (reused for VT after V gemm)
  unsigned short* Wob  = (unsigned short*)(ws + 67108864);    // 33.5 MB
  unsigned short* Qb   = (unsigned short*)(ws + 100663296);   // 16.8 MB
  unsigned short* Kbuf = (unsigned short*)(ws + 117440512);   // 4.2 MB
  unsigned short* Vbuf = (unsigned short*)(ws + 121634816);   // 4.2 MB
  unsigned short* Ab   = (unsigned short*)(ws + 125829120);   // 16.8 MB  (total 142.6 MB)
  unsigned short* VT   = Wvb;                                 // 4.2 MB, Wvb dead after V gemm

  cvt_bf16<<<8388608/1024, 256, 0, stream>>>(x,  xb,  8388608/4);
  cvt_bf16<<<16777216/1024, 256, 0, stream>>>(Wq, Wqb, 16777216/4);
  cvt_bf16<<<4194304/1024, 256, 0, stream>>>(Wk, Wkb, 4194304/4);
  cvt_bf16<<<4194304/1024, 256, 0, stream>>>(Wv, Wvb, 4194304/4);
  cvt_bf16<<<16777216/1024, 256, 0, stream>>>(Wo, Wob, 16777216/4);

  gemm_bt<1><<<dim3(32, 16), 256, 0, stream>>>(xb, Wqb, Qb,   2048, 4096, 4096);
  gemm_bt<1><<<dim3(8, 16),  256, 0, stream>>>(xb, Wkb, Kbuf, 2048, 1024, 4096);
  gemm_bt<1><<<dim3(8, 16),  256, 0, stream>>>(xb, Wvb, Vbuf, 2048, 1024, 4096);

  transpose_v<<<dim3(32, 16), 256, 0, stream>>>(Vbuf, VT);

  rope_inplace<<<16384, 256, 0, stream>>>(Qb,   cosb, sinb, NH);
  rope_inplace<<<4096,  256, 0, stream>>>(Kbuf, cosb, sinb, NKV);

  attn_fwd<<<dim3(16, 32), 256, 0, stream>>>(Qb, Kbuf, VT, Ab);

  gemm_bt<0><<<dim3(32, 16), 256, 0, stream>>>(Ab, Wob, d_out, 2048, 4096, 4096);
}

// Round 3
// 599.618 us; speedup vs baseline: 1.4635x; 1.1495x over previous
//
#include <hip/hip_runtime.h>

#define S_LEN 2048
#define DMODEL 4096
#define NH 32
#define NKV 8
#define DH 128
#define QDIM (NH*DH)      // 4096
#define NQKV 6144         // fused projection width
#define SCALE 0.08838834764831845f

typedef __attribute__((ext_vector_type(8))) short short8;
typedef __attribute__((ext_vector_type(4))) float f32x4;
typedef __attribute__((ext_vector_type(4))) unsigned short us4;

__device__ __forceinline__ unsigned short f2bf(float f) {
  union { float f; unsigned int u; } v; v.f = f;
  unsigned int r = v.u + 0x7FFFu + ((v.u >> 16) & 1u);
  return (unsigned short)(r >> 16);
}
__device__ __forceinline__ float bf2f(unsigned short h) {
  union { unsigned int u; float f; } v; v.u = ((unsigned int)h) << 16;
  return v.f;
}

// ---------------- f32 -> bf16 convert (4 elems/thread) ----------------
__global__ __launch_bounds__(256) void cvt_bf16(const float* __restrict__ in,
                                                unsigned short* __restrict__ out, int n4) {
  int i = blockIdx.x * 256 + threadIdx.x;
  if (i >= n4) return;
  const float4 f = reinterpret_cast<const float4*>(in)[i];
  us4 o;
  o.x = f2bf(f.x); o.y = f2bf(f.y); o.z = f2bf(f.z); o.w = f2bf(f.w);
  reinterpret_cast<us4*>(out)[i] = o;
}

// ---------------- GEMM: C[M,N] = A[M,K] * B[N,K]^T  (m97-style 128x128) ----------------
template<int OUT_BF16>
__global__ __launch_bounds__(256) void gemm_bt(const unsigned short* __restrict__ A,
                                               const unsigned short* __restrict__ B,
                                               void* __restrict__ Cv,
                                               int M, int N, int K) {
  __shared__ unsigned short lds[8192]; // A tile [128][32] @0, B tile [128][32] @4096
  const int tid = threadIdx.x;
  const int lane = tid & 63;
  const int wave = tid >> 6;
  const int wr = wave >> 1, wc = wave & 1;
  const int fr = lane & 15, fq = lane >> 4;
  const long m0 = (long)blockIdx.y * 128;
  const long n0 = (long)blockIdx.x * 128;
  const int srow = tid >> 2;
  const int scol = (tid & 3) * 8;

  f32x4 acc[4][4] = {};

  for (int k0 = 0; k0 < K; k0 += 32) {
#pragma unroll
    for (int i = 0; i < 2; ++i) {
      __builtin_amdgcn_global_load_lds(
          (const __attribute__((address_space(1))) void*)(A + (m0 + i*64 + srow) * (long)K + k0 + scol),
          (__attribute__((address_space(3))) void*)((char*)lds + i*4096 + tid*16),
          16, 0, 0);
      __builtin_amdgcn_global_load_lds(
          (const __attribute__((address_space(1))) void*)(B + (n0 + i*64 + srow) * (long)K + k0 + scol),
          (__attribute__((address_space(3))) void*)((char*)lds + 8192 + i*4096 + tid*16),
          16, 0, 0);
    }
    __syncthreads();

    short8 a[4], b[4];
#pragma unroll
    for (int m = 0; m < 4; ++m)
      a[m] = *reinterpret_cast<const short8*>(lds + (wr*64 + m*16 + fr)*32 + fq*8);
#pragma unroll
    for (int n = 0; n < 4; ++n)
      b[n] = *reinterpret_cast<const short8*>(lds + 4096 + (wc*64 + n*16 + fr)*32 + fq*8);
#pragma unroll
    for (int m = 0; m < 4; ++m)
#pragma unroll
      for (int n = 0; n < 4; ++n)
        acc[m][n] = __builtin_amdgcn_mfma_f32_16x16x32_bf16(a[m], b[n], acc[m][n], 0, 0, 0);
    __syncthreads();
  }

#pragma unroll
  for (int m = 0; m < 4; ++m) {
#pragma unroll
    for (int n = 0; n < 4; ++n) {
#pragma unroll
      for (int j = 0; j < 4; ++j) {
        long r = m0 + wr*64 + m*16 + fq*4 + j;
        long c = n0 + wc*64 + n*16 + fr;
        float v = acc[m][n][j];
        if (OUT_BF16) ((unsigned short*)Cv)[r * (long)N + c] = f2bf(v);
        else          ((float*)Cv)[r * (long)N + c] = v;
      }
    }
  }
}

// ---------------- YaRN RoPE in-place on fused QKV buffer (stride 6144) ----------------
// 40 rope-heads: 0..31 = Q heads (also folds in 1/sqrt(Dh)); 32..39 = K heads.
__global__ __launch_bounds__(256) void rope_fused(unsigned short* __restrict__ C,
                                                  const float* __restrict__ cosb,
                                                  const float* __restrict__ sinb) {
  int idx = blockIdx.x * 256 + threadIdx.x;
  int i = idx & 63;
  int t = idx >> 6;       // s*40 + hh
  int hh = t % 40;
  int s = t / 40;
  const bool isQ = hh < 32;
  unsigned short* row = C + (size_t)s * NQKV + (isQ ? hh * DH : 4096 + (hh - 32) * DH);
  float sc = isQ ? SCALE : 1.0f;
  float c  = cosb[s * DH + i];
  float sn = sinb[s * DH + i];
  float x1 = bf2f(row[i]);
  float x2 = bf2f(row[i + 64]);
  row[i]      = f2bf((x1 * c - x2 * sn) * sc);
  row[i + 64] = f2bf((x2 * c + x1 * sn) * sc);
}

// ---------------- V transpose: C[s][5120+e] -> VT[kvh][d][s] ----------------
__global__ __launch_bounds__(256) void transpose_v(const unsigned short* __restrict__ Vbuf,
                                                   unsigned short* __restrict__ VT) {
  __shared__ unsigned short t[64][72];
  const int s0 = blockIdx.x * 64, e0 = blockIdx.y * 64;
  const int r = threadIdx.x >> 3, c = (threadIdx.x & 7) * 8;
#pragma unroll
  for (int half = 0; half < 2; ++half) {
    int row = r + half * 32;
    *reinterpret_cast<short8*>(&t[row][c]) =
        *reinterpret_cast<const short8*>(Vbuf + (size_t)(s0 + row) * NQKV + e0 + c);
  }
  __syncthreads();
  const int hh = e0 >> 7, dbase = e0 & 127;
#pragma unroll
  for (int half = 0; half < 2; ++half) {
    int row = r + half * 32;   // d offset within the 64-col slab
    short8 o;
#pragma unroll
    for (int j = 0; j < 8; ++j) ((unsigned short*)&o)[j] = t[c + j][row];
    *reinterpret_cast<short8*>(VT + (size_t)hh * (DH * (size_t)S_LEN)
                               + (size_t)(dbase + row) * S_LEN + s0 + c) = o;
  }
}

// ---------------- GQA causal flash attention, L2-direct (no K/V LDS, no barriers) ----
// grid: 1024 blocks x 256 thr. Block remap: kvh = lin&7 (XCD locality), LPT on q-blocks.
// 4 independent waves/block; wave owns 16 q rows. KVBLK=64.
__global__ __launch_bounds__(256) void attn_fwd(const unsigned short* __restrict__ C,
                                                const unsigned short* __restrict__ VT,
                                                unsigned short* __restrict__ Ob) {
  __shared__ unsigned short Pl[4][16 * 72];
  const int tid = threadIdx.x;
  const int lane = tid & 63;
  const int wave = tid >> 6;
  const int lin = blockIdx.x;
  const int kvh = lin & 7;
  const int inner = lin >> 3;              // 0..127
  const int h = kvh * 4 + (inner & 3);
  const int qbi = 31 - (inner >> 2);       // heavy blocks first
  const int q0 = qbi * 64 + wave * 16;
  const int fr = lane & 15, fq = lane >> 4;

  const unsigned short* Qbase = C + (size_t)h * DH;
  const unsigned short* Kbase = C + 4096 + (size_t)kvh * DH;
  const unsigned short* Vbase = VT + (size_t)kvh * (DH * (size_t)S_LEN);

  // Q fragments (Q is pre-scaled by 1/sqrt(Dh) in rope_fused)
  short8 qf[4];
#pragma unroll
  for (int dc = 0; dc < 4; ++dc)
    qf[dc] = *reinterpret_cast<const short8*>(
        Qbase + (size_t)(q0 + fr) * NQKV + dc * 32 + fq * 8);

  f32x4 o_acc[8] = {};
  float mrow[4] = {-1e30f, -1e30f, -1e30f, -1e30f};
  float lpart[4] = {0.f, 0.f, 0.f, 0.f};

  for (int kv0 = 0; kv0 < q0 + 16; kv0 += 64) {
    // ---- QK^T: S[16 q][64 kv], K fragments straight from L2 ----
    f32x4 sacc[4] = {};
#pragma unroll
    for (int nt = 0; nt < 4; ++nt)
#pragma unroll
      for (int dc = 0; dc < 4; ++dc) {
        short8 kf = *reinterpret_cast<const short8*>(
            Kbase + (size_t)(kv0 + nt*16 + fr) * NQKV + dc * 32 + fq * 8);
        sacc[nt] = __builtin_amdgcn_mfma_f32_16x16x32_bf16(qf[dc], kf, sacc[nt], 0, 0, 0);
      }

    // ---- online softmax (defer-max, per-lane partial sums) ----
    const bool needMask = (kv0 + 64 > q0);
    float tm[4];
#pragma unroll
    for (int j = 0; j < 4; ++j) {
      if (needMask) {
        int qrow = q0 + fq * 4 + j;
#pragma unroll
        for (int nt = 0; nt < 4; ++nt)
          sacc[nt][j] = ((kv0 + nt*16 + fr) <= qrow) ? sacc[nt][j] : -1e30f;
      }
      float t = fmaxf(fmaxf(sacc[0][j], sacc[1][j]), fmaxf(sacc[2][j], sacc[3][j]));
      t = fmaxf(t, __shfl_xor(t, 1));
      t = fmaxf(t, __shfl_xor(t, 2));
      t = fmaxf(t, __shfl_xor(t, 4));
      t = fmaxf(t, __shfl_xor(t, 8));
      tm[j] = t;
    }
    bool noResc = (tm[0] <= mrow[0] + 8.f) && (tm[1] <= mrow[1] + 8.f)
               && (tm[2] <= mrow[2] + 8.f) && (tm[3] <= mrow[3] + 8.f);
    if (!__all(noResc)) {
#pragma unroll
      for (int j = 0; j < 4; ++j) {
        float mnew = fmaxf(mrow[j], tm[j]);
        float corr = __expf(mrow[j] - mnew);
        mrow[j] = mnew;
        lpart[j] *= corr;
#pragma unroll
        for (int dt = 0; dt < 8; ++dt) o_acc[dt][j] *= corr;
      }
    }
#pragma unroll
    for (int j = 0; j < 4; ++j) {
      float msub = mrow[j];
      float ls = 0.f;
#pragma unroll
      for (int nt = 0; nt < 4; ++nt) {
        float p = __expf(sacc[nt][j] - msub);   // masked -> 0
        ls += p;
        Pl[wave][(fq*4 + j)*72 + nt*16 + fr] = f2bf(p);
      }
      lpart[j] += ls;
    }
    asm volatile("s_waitcnt lgkmcnt(0)" ::: "memory");
    __builtin_amdgcn_sched_barrier(0);

    // ---- PV: O += P[16 q][64 kv] * V^T fragments straight from L2 ----
#pragma unroll
    for (int ks = 0; ks < 2; ++ks) {
      short8 pa = *reinterpret_cast<const short8*>(&Pl[wave][fr*72 + ks*32 + fq*8]);
#pragma unroll
      for (int dt = 0; dt < 8; ++dt) {
        short8 bv = *reinterpret_cast<const short8*>(
            Vbase + (size_t)(dt*16 + fr) * S_LEN + kv0 + ks*32 + fq*8);
        o_acc[dt] = __builtin_amdgcn_mfma_f32_16x16x32_bf16(pa, bv, o_acc[dt], 0, 0, 0);
      }
    }
  }

  // epilogue: reduce row sums across fr lanes, normalize, store
#pragma unroll
  for (int j = 0; j < 4; ++j) {
    float l = lpart[j];
    l += __shfl_xor(l, 1);
    l += __shfl_xor(l, 2);
    l += __shfl_xor(l, 4);
    l += __shfl_xor(l, 8);
    float inv = 1.f / l;
    size_t r = (size_t)q0 + fq*4 + j;
#pragma unroll
    for (int dt = 0; dt < 8; ++dt)
      Ob[r * QDIM + h * DH + dt*16 + fr] = f2bf(o_acc[dt][j] * inv);
  }
}

// ---------------- launch ----------------
extern "C" void kernel_launch(void* const* d_in, const int* in_sizes, int n_in,
                              void* d_out, int out_size, void* d_ws, size_t ws_size,
                              hipStream_t stream) {
  (void)in_sizes; (void)n_in; (void)out_size; (void)ws_size;
  const float* x    = (const float*)d_in[0];
  const float* Wq   = (const float*)d_in[1];
  const float* Wk   = (const float*)d_in[2];
  const float* Wv   = (const float*)d_in[3];
  const float* Wo   = (const float*)d_in[4];
  const float* cosb = (const float*)d_in[5];
  const float* sinb = (const float*)d_in[6];

  char* ws = (char*)d_ws;
  unsigned short* xb    = (unsigned short*)(ws);               // 16.8 MB (dead after QKV gemm)
  unsigned short* Wqkvb = (unsigned short*)(ws + 16777216);    // 50.3 MB [Wq;Wk;Wv]
  unsigned short* Wob   = (unsigned short*)(ws + 67108864);    // 33.6 MB
  unsigned short* Cqkv  = (unsigned short*)(ws + 100663296);   // 25.2 MB [Q|K|V] stride 6144
  unsigned short* VT    = (unsigned short*)(ws + 125829120);   // 4.2 MB  (total 130.0 MB)
  unsigned short* Ab    = xb;                                  // reuse

  cvt_bf16<<<8192,  256, 0, stream>>>(x,  xb, 2097152);
  cvt_bf16<<<16384, 256, 0, stream>>>(Wq, Wqkvb,            4194304);
  cvt_bf16<<<4096,  256, 0, stream>>>(Wk, Wqkvb + 16777216, 1048576);
  cvt_bf16<<<4096,  256, 0, stream>>>(Wv, Wqkvb + 20971520, 1048576);
  cvt_bf16<<<16384, 256, 0, stream>>>(Wo, Wob, 4194304);

  gemm_bt<1><<<dim3(48, 16), 256, 0, stream>>>(xb, Wqkvb, Cqkv, 2048, NQKV, 4096);

  rope_fused<<<20480, 256, 0, stream>>>(Cqkv, cosb, sinb);
  transpose_v<<<dim3(32, 16), 256, 0, stream>>>(Cqkv + 5120, VT);

  attn_fwd<<<1024, 256, 0, stream>>>(Cqkv, VT, Ab);

  gemm_bt<0><<<dim3(32, 16), 256, 0, stream>>>(Ab, Wob, d_out, 2048, 4096, 4096);
}

// Round 4
// 460.985 us; speedup vs baseline: 1.9037x; 1.3007x over previous
//
#include <hip/hip_runtime.h>

#define S_LEN 2048
#define DMODEL 4096
#define NH 32
#define NKV 8
#define DH 128
#define QDIM (NH*DH)      // 4096
#define NQKV 6144         // fused projection width
#define SCALE 0.08838834764831845f

typedef __attribute__((ext_vector_type(8))) short short8;
typedef __attribute__((ext_vector_type(4))) float f32x4;
typedef __attribute__((ext_vector_type(4))) unsigned short us4;

__device__ __forceinline__ unsigned short f2bf(float f) {
  union { float f; unsigned int u; } v; v.f = f;
  unsigned int r = v.u + 0x7FFFu + ((v.u >> 16) & 1u);
  return (unsigned short)(r >> 16);
}
__device__ __forceinline__ float bf2f(unsigned short h) {
  union { unsigned int u; float f; } v; v.u = ((unsigned int)h) << 16;
  return v.f;
}

// ---------------- f32 -> bf16 convert (4 elems/thread) ----------------
__global__ __launch_bounds__(256) void cvt_bf16(const float* __restrict__ in,
                                                unsigned short* __restrict__ out, int n4) {
  int i = blockIdx.x * 256 + threadIdx.x;
  if (i >= n4) return;
  const float4 f = reinterpret_cast<const float4*>(in)[i];
  us4 o;
  o.x = f2bf(f.x); o.y = f2bf(f.y); o.z = f2bf(f.z); o.w = f2bf(f.w);
  reinterpret_cast<us4*>(out)[i] = o;
}

// ---------------- GEMM: C[M,N] = A[M,K] * B[N,K]^T  (m97-style 128x128) ----------------
template<int OUT_BF16>
__global__ __launch_bounds__(256) void gemm_bt(const unsigned short* __restrict__ A,
                                               const unsigned short* __restrict__ B,
                                               void* __restrict__ Cv,
                                               int M, int N, int K) {
  __shared__ unsigned short lds[8192]; // A tile [128][32] @0, B tile [128][32] @4096
  const int tid = threadIdx.x;
  const int lane = tid & 63;
  const int wave = tid >> 6;
  const int wr = wave >> 1, wc = wave & 1;
  const int fr = lane & 15, fq = lane >> 4;
  const long m0 = (long)blockIdx.y * 128;
  const long n0 = (long)blockIdx.x * 128;
  const int srow = tid >> 2;
  const int scol = (tid & 3) * 8;

  f32x4 acc[4][4] = {};

  for (int k0 = 0; k0 < K; k0 += 32) {
#pragma unroll
    for (int i = 0; i < 2; ++i) {
      __builtin_amdgcn_global_load_lds(
          (const __attribute__((address_space(1))) void*)(A + (m0 + i*64 + srow) * (long)K + k0 + scol),
          (__attribute__((address_space(3))) void*)((char*)lds + i*4096 + tid*16),
          16, 0, 0);
      __builtin_amdgcn_global_load_lds(
          (const __attribute__((address_space(1))) void*)(B + (n0 + i*64 + srow) * (long)K + k0 + scol),
          (__attribute__((address_space(3))) void*)((char*)lds + 8192 + i*4096 + tid*16),
          16, 0, 0);
    }
    __syncthreads();

    short8 a[4], b[4];
#pragma unroll
    for (int m = 0; m < 4; ++m)
      a[m] = *reinterpret_cast<const short8*>(lds + (wr*64 + m*16 + fr)*32 + fq*8);
#pragma unroll
    for (int n = 0; n < 4; ++n)
      b[n] = *reinterpret_cast<const short8*>(lds + 4096 + (wc*64 + n*16 + fr)*32 + fq*8);
#pragma unroll
    for (int m = 0; m < 4; ++m)
#pragma unroll
      for (int n = 0; n < 4; ++n)
        acc[m][n] = __builtin_amdgcn_mfma_f32_16x16x32_bf16(a[m], b[n], acc[m][n], 0, 0, 0);
    __syncthreads();
  }

#pragma unroll
  for (int m = 0; m < 4; ++m) {
#pragma unroll
    for (int n = 0; n < 4; ++n) {
#pragma unroll
      for (int j = 0; j < 4; ++j) {
        long r = m0 + wr*64 + m*16 + fq*4 + j;
        long c = n0 + wc*64 + n*16 + fr;
        float v = acc[m][n][j];
        if (OUT_BF16) ((unsigned short*)Cv)[r * (long)N + c] = f2bf(v);
        else          ((float*)Cv)[r * (long)N + c] = v;
      }
    }
  }
}

// ---------------- YaRN RoPE in-place on fused QKV buffer (stride 6144) ----------------
// 40 rope-heads: 0..31 = Q heads (also folds in 1/sqrt(Dh)); 32..39 = K heads.
__global__ __launch_bounds__(256) void rope_fused(unsigned short* __restrict__ C,
                                                  const float* __restrict__ cosb,
                                                  const float* __restrict__ sinb) {
  int idx = blockIdx.x * 256 + threadIdx.x;
  int i = idx & 63;
  int t = idx >> 6;       // s*40 + hh
  int hh = t % 40;
  int s = t / 40;
  const bool isQ = hh < 32;
  unsigned short* row = C + (size_t)s * NQKV + (isQ ? hh * DH : 4096 + (hh - 32) * DH);
  float sc = isQ ? SCALE : 1.0f;
  float c  = cosb[s * DH + i];
  float sn = sinb[s * DH + i];
  float x1 = bf2f(row[i]);
  float x2 = bf2f(row[i + 64]);
  row[i]      = f2bf((x1 * c - x2 * sn) * sc);
  row[i + 64] = f2bf((x2 * c + x1 * sn) * sc);
}

// ---------------- V transpose: C[s][5120+e] -> VT[kvh][d][s] ----------------
__global__ __launch_bounds__(256) void transpose_v(const unsigned short* __restrict__ Vbuf,
                                                   unsigned short* __restrict__ VT) {
  __shared__ unsigned short t[64][72];
  const int s0 = blockIdx.x * 64, e0 = blockIdx.y * 64;
  const int r = threadIdx.x >> 3, c = (threadIdx.x & 7) * 8;
#pragma unroll
  for (int half = 0; half < 2; ++half) {
    int row = r + half * 32;
    *reinterpret_cast<short8*>(&t[row][c]) =
        *reinterpret_cast<const short8*>(Vbuf + (size_t)(s0 + row) * NQKV + e0 + c);
  }
  __syncthreads();
  const int hh = e0 >> 7, dbase = e0 & 127;
#pragma unroll
  for (int half = 0; half < 2; ++half) {
    int row = r + half * 32;   // d offset within the 64-col slab
    short8 o;
#pragma unroll
    for (int j = 0; j < 8; ++j) ((unsigned short*)&o)[j] = t[c + j][row];
    *reinterpret_cast<short8*>(VT + (size_t)hh * (DH * (size_t)S_LEN)
                               + (size_t)(dbase + row) * S_LEN + s0 + c) = o;
  }
}

// ---------------- GQA causal flash attention ----------------
// Block = 4 waves = the 4 q-heads of one kv-group (shared K/V LDS, staged once).
// Each wave processes TWO 16-row q-strips: p and 127-p (uniform work: ~33 strip-tiles).
// Grid = 512 blocks (kvh = blockIdx&7 for XCD L2 locality) = exactly 2 blocks/CU.
// 2-phase pipeline: stage(t+1) issued before compute(t); one vmcnt(0)+barrier per tile.
__global__ __launch_bounds__(256) void attn_fwd(const unsigned short* __restrict__ C,
                                                const unsigned short* __restrict__ VT,
                                                unsigned short* __restrict__ Ob) {
  __shared__ unsigned short KVs[2][16384];   // per buf: K[64][128] swz @0, V[128][64] swz @16KB
  __shared__ unsigned short Pl[4][16 * 72];  // per-wave P, reused across strips
  const int tid = threadIdx.x, lane = tid & 63, wave = tid >> 6;
  const int kvh = blockIdx.x & 7;
  const int p = blockIdx.x >> 3;             // 0..63
  const int h = kvh * 4 + wave;
  const int fr = lane & 15, fq = lane >> 4;
  const int q0s[2] = { p * 16, (127 - p) * 16 };
  const int tilesA = (p + 4) >> 2;           // ceil((p+1)/4)
  const int tilesB = (131 - p) >> 2;         // ceil((128-p)/4)

  const unsigned short* Qbase = C + (size_t)h * DH;
  const unsigned short* Kbase = C + 4096 + (size_t)kvh * DH;
  const unsigned short* Vbase = VT + (size_t)kvh * (DH * (size_t)S_LEN);

  // Q fragments for both strips (Q pre-scaled by 1/sqrt(Dh) in rope_fused)
  short8 qf[2][4];
#pragma unroll
  for (int s = 0; s < 2; ++s)
#pragma unroll
    for (int dc = 0; dc < 4; ++dc)
      qf[s][dc] = *reinterpret_cast<const short8*>(
          Qbase + (size_t)(q0s[s] + fr) * NQKV + dc * 32 + fq * 8);

  f32x4 o_acc[2][8] = {};
  float mrow[2][4] = {{-1e30f,-1e30f,-1e30f,-1e30f},{-1e30f,-1e30f,-1e30f,-1e30f}};
  float lpart[2][4] = {};

  auto STAGE = [&](int t, int buf) {
    const int kv0 = t * 64;
    char* dst = (char*)&KVs[buf][0];
#pragma unroll
    for (int sh = 0; sh < 4; ++sh) {
      int b = sh * 4096 + tid * 16;
      int krow = b >> 8;
      int kcol = (b & 255) ^ ((krow & 7) << 4);
      __builtin_amdgcn_global_load_lds(
          (const __attribute__((address_space(1))) void*)(Kbase + (size_t)(kv0 + krow) * NQKV + (kcol >> 1)),
          (__attribute__((address_space(3))) void*)(dst + b), 16, 0, 0);
      int vrow = b >> 7;
      int vcol = (b & 127) ^ ((vrow & 7) << 4);
      __builtin_amdgcn_global_load_lds(
          (const __attribute__((address_space(1))) void*)(Vbase + (size_t)vrow * S_LEN + kv0 + (vcol >> 1)),
          (__attribute__((address_space(3))) void*)(dst + 16384 + b), 16, 0, 0);
    }
  };

  int cur = 0;
  STAGE(0, 0);
  asm volatile("s_waitcnt vmcnt(0)" ::: "memory");
  __syncthreads();

  for (int t = 0; t < tilesB; ++t) {
    const int kv0 = t * 64;
    if (t + 1 < tilesB) STAGE(t + 1, cur ^ 1);
    const char* kvb = (const char*)&KVs[cur][0];

#pragma unroll
    for (int s = 0; s < 2; ++s) {
      if (s == 0 && t >= tilesA) continue;
      const int q0 = q0s[s];

      // ---- QK^T: S[16 q][64 kv] from swizzled K LDS ----
      f32x4 sacc[4] = {};
#pragma unroll
      for (int nt = 0; nt < 4; ++nt) {
        const int row = nt * 16 + fr;
#pragma unroll
        for (int dc = 0; dc < 4; ++dc) {
          short8 kf = *reinterpret_cast<const short8*>(
              kvb + row * 256 + ((dc * 64 + fq * 16) ^ ((row & 7) << 4)));
          sacc[nt] = __builtin_amdgcn_mfma_f32_16x16x32_bf16(qf[s][dc], kf, sacc[nt], 0, 0, 0);
        }
      }

      // ---- online softmax (defer-max, per-lane partial sums) ----
      const bool needMask = (kv0 + 64 > q0);
      float tm[4];
#pragma unroll
      for (int j = 0; j < 4; ++j) {
        if (needMask) {
          int qrow = q0 + fq * 4 + j;
#pragma unroll
          for (int nt = 0; nt < 4; ++nt)
            sacc[nt][j] = ((kv0 + nt*16 + fr) <= qrow) ? sacc[nt][j] : -1e30f;
        }
        float tmx = fmaxf(fmaxf(sacc[0][j], sacc[1][j]), fmaxf(sacc[2][j], sacc[3][j]));
        tmx = fmaxf(tmx, __shfl_xor(tmx, 1));
        tmx = fmaxf(tmx, __shfl_xor(tmx, 2));
        tmx = fmaxf(tmx, __shfl_xor(tmx, 4));
        tmx = fmaxf(tmx, __shfl_xor(tmx, 8));
        tm[j] = tmx;
      }
      bool noResc = (tm[0] <= mrow[s][0] + 8.f) && (tm[1] <= mrow[s][1] + 8.f)
                 && (tm[2] <= mrow[s][2] + 8.f) && (tm[3] <= mrow[s][3] + 8.f);
      if (!__all(noResc)) {
#pragma unroll
        for (int j = 0; j < 4; ++j) {
          float mnew = fmaxf(mrow[s][j], tm[j]);
          float corr = __expf(mrow[s][j] - mnew);
          mrow[s][j] = mnew;
          lpart[s][j] *= corr;
#pragma unroll
          for (int dt = 0; dt < 8; ++dt) o_acc[s][dt][j] *= corr;
        }
      }
#pragma unroll
      for (int j = 0; j < 4; ++j) {
        float msub = mrow[s][j];
        float ls = 0.f;
#pragma unroll
        for (int nt = 0; nt < 4; ++nt) {
          float pe = __expf(sacc[nt][j] - msub);   // masked -> 0
          ls += pe;
          Pl[wave][(fq*4 + j)*72 + nt*16 + fr] = f2bf(pe);
        }
        lpart[s][j] += ls;
      }
      asm volatile("s_waitcnt lgkmcnt(0)" ::: "memory");
      __builtin_amdgcn_sched_barrier(0);

      // ---- PV: O += P[16 q][64 kv] * V[64 kv][128 d] from swizzled V LDS ----
#pragma unroll
      for (int ks = 0; ks < 2; ++ks) {
        short8 pa = *reinterpret_cast<const short8*>(&Pl[wave][fr*72 + ks*32 + fq*8]);
#pragma unroll
        for (int dt = 0; dt < 8; ++dt) {
          const int row = dt * 16 + fr;
          short8 bv = *reinterpret_cast<const short8*>(
              kvb + 16384 + row * 128 + ((ks * 64 + fq * 16) ^ ((row & 7) << 4)));
          o_acc[s][dt] = __builtin_amdgcn_mfma_f32_16x16x32_bf16(pa, bv, o_acc[s][dt], 0, 0, 0);
        }
      }
    }

    asm volatile("s_waitcnt vmcnt(0)" ::: "memory");
    __syncthreads();
    cur ^= 1;
  }

  // epilogue: reduce row sums across fr lanes, normalize, store both strips
#pragma unroll
  for (int s = 0; s < 2; ++s)
#pragma unroll
    for (int j = 0; j < 4; ++j) {
      float l = lpart[s][j];
      l += __shfl_xor(l, 1);
      l += __shfl_xor(l, 2);
      l += __shfl_xor(l, 4);
      l += __shfl_xor(l, 8);
      float inv = 1.f / l;
      size_t r = (size_t)q0s[s] + fq*4 + j;
#pragma unroll
      for (int dt = 0; dt < 8; ++dt)
        Ob[r * QDIM + h * DH + dt*16 + fr] = f2bf(o_acc[s][dt][j] * inv);
    }
}

// ---------------- launch ----------------
extern "C" void kernel_launch(void* const* d_in, const int* in_sizes, int n_in,
                              void* d_out, int out_size, void* d_ws, size_t ws_size,
                              hipStream_t stream) {
  (void)in_sizes; (void)n_in; (void)out_size; (void)ws_size;
  const float* x    = (const float*)d_in[0];
  const float* Wq   = (const float*)d_in[1];
  const float* Wk   = (const float*)d_in[2];
  const float* Wv   = (const float*)d_in[3];
  const float* Wo   = (const float*)d_in[4];
  const float* cosb = (const float*)d_in[5];
  const float* sinb = (const float*)d_in[6];

  char* ws = (char*)d_ws;
  unsigned short* xb    = (unsigned short*)(ws);               // 16.8 MB (dead after QKV gemm)
  unsigned short* Wqkvb = (unsigned short*)(ws + 16777216);    // 50.3 MB [Wq;Wk;Wv]
  unsigned short* Wob   = (unsigned short*)(ws + 67108864);    // 33.6 MB
  unsigned short* Cqkv  = (unsigned short*)(ws + 100663296);   // 25.2 MB [Q|K|V] stride 6144
  unsigned short* VT    = (unsigned short*)(ws + 125829120);   // 4.2 MB  (total 130.0 MB)
  unsigned short* Ab    = xb;                                  // reuse

  cvt_bf16<<<8192,  256, 0, stream>>>(x,  xb, 2097152);
  cvt_bf16<<<16384, 256, 0, stream>>>(Wq, Wqkvb,            4194304);
  cvt_bf16<<<4096,  256, 0, stream>>>(Wk, Wqkvb + 16777216, 1048576);
  cvt_bf16<<<4096,  256, 0, stream>>>(Wv, Wqkvb + 20971520, 1048576);
  cvt_bf16<<<16384, 256, 0, stream>>>(Wo, Wob, 4194304);

  gemm_bt<1><<<dim3(48, 16), 256, 0, stream>>>(xb, Wqkvb, Cqkv, 2048, NQKV, 4096);

  rope_fused<<<20480, 256, 0, stream>>>(Cqkv, cosb, sinb);
  transpose_v<<<dim3(32, 16), 256, 0, stream>>>(Cqkv + 5120, VT);

  attn_fwd<<<512, 256, 0, stream>>>(Cqkv, VT, Ab);

  gemm_bt<0><<<dim3(32, 16), 256, 0, stream>>>(Ab, Wob, d_out, 2048, 4096, 4096);
}

// Round 6
// 393.000 us; speedup vs baseline: 2.2330x; 1.1730x over previous
//
#include <hip/hip_runtime.h>

#define S_LEN 2048
#define DMODEL 4096
#define NH 32
#define NKV 8
#define DH 128
#define QDIM (NH*DH)      // 4096
#define NQKV 6144         // fused projection width
#define SCALE 0.08838834764831845f

typedef __attribute__((ext_vector_type(8))) short short8;
typedef __attribute__((ext_vector_type(4))) float f32x4;
typedef __attribute__((ext_vector_type(4))) unsigned short us4;

__device__ __forceinline__ unsigned short f2bf(float f) {
  union { float f; unsigned int u; } v; v.f = f;
  unsigned int r = v.u + 0x7FFFu + ((v.u >> 16) & 1u);
  return (unsigned short)(r >> 16);
}
__device__ __forceinline__ float bf2f(unsigned short h) {
  union { unsigned int u; float f; } v; v.u = ((unsigned int)h) << 16;
  return v.f;
}

// ---------------- fused f32 -> bf16 convert for all 5 tensors ----------------
__global__ __launch_bounds__(256) void cvt_all(const float* __restrict__ x,
                                               const float* __restrict__ Wq,
                                               const float* __restrict__ Wk,
                                               const float* __restrict__ Wv,
                                               const float* __restrict__ Wo,
                                               unsigned short* __restrict__ xb,
                                               unsigned short* __restrict__ Wqkvb,
                                               unsigned short* __restrict__ Wob) {
  const int blk = blockIdx.x;
  const float* src; unsigned short* dst; int off;
  if (blk < 8192)       { src = x;  dst = xb;               off = blk; }
  else if (blk < 24576) { src = Wq; dst = Wqkvb;            off = blk - 8192; }
  else if (blk < 28672) { src = Wk; dst = Wqkvb + 16777216; off = blk - 24576; }
  else if (blk < 32768) { src = Wv; dst = Wqkvb + 20971520; off = blk - 28672; }
  else                  { src = Wo; dst = Wob;              off = blk - 32768; }
  int i = off * 256 + threadIdx.x;
  const float4 f = reinterpret_cast<const float4*>(src)[i];
  us4 o;
  o.x = f2bf(f.x); o.y = f2bf(f.y); o.z = f2bf(f.z); o.w = f2bf(f.w);
  reinterpret_cast<us4*>(dst)[i] = o;
}

// ---------------- GEMM: C[M,N] = A[M,K] * B[N,K]^T  (m97-style 128x128, T1 swizzle) ----
template<int OUT_BF16>
__global__ __launch_bounds__(256) void gemm_bt(const unsigned short* __restrict__ A,
                                               const unsigned short* __restrict__ B,
                                               void* __restrict__ Cv,
                                               int M, int N, int K) {
  __shared__ unsigned short lds[8192]; // A tile [128][32] @0, B tile [128][32] @4096
  const int tid = threadIdx.x;
  const int lane = tid & 63;
  const int wave = tid >> 6;
  const int wr = wave >> 1, wc = wave & 1;
  const int fr = lane & 15, fq = lane >> 4;
  // XCD-chunked tile remap (grid size % 8 == 0): XCD k owns a contiguous tile range.
  const int nb = gridDim.x * gridDim.y;
  const int lin = blockIdx.y * gridDim.x + blockIdx.x;
  const int nl = (lin & 7) * (nb >> 3) + (lin >> 3);
  const long m0 = (long)(nl / gridDim.x) * 128;
  const long n0 = (long)(nl % gridDim.x) * 128;
  const int srow = tid >> 2;
  const int scol = (tid & 3) * 8;

  f32x4 acc[4][4] = {};

  for (int k0 = 0; k0 < K; k0 += 32) {
#pragma unroll
    for (int i = 0; i < 2; ++i) {
      __builtin_amdgcn_global_load_lds(
          (const __attribute__((address_space(1))) void*)(A + (m0 + i*64 + srow) * (long)K + k0 + scol),
          (__attribute__((address_space(3))) void*)((char*)lds + i*4096 + tid*16),
          16, 0, 0);
      __builtin_amdgcn_global_load_lds(
          (const __attribute__((address_space(1))) void*)(B + (n0 + i*64 + srow) * (long)K + k0 + scol),
          (__attribute__((address_space(3))) void*)((char*)lds + 8192 + i*4096 + tid*16),
          16, 0, 0);
    }
    __syncthreads();

    short8 a[4], b[4];
#pragma unroll
    for (int m = 0; m < 4; ++m)
      a[m] = *reinterpret_cast<const short8*>(lds + (wr*64 + m*16 + fr)*32 + fq*8);
#pragma unroll
    for (int n = 0; n < 4; ++n)
      b[n] = *reinterpret_cast<const short8*>(lds + 4096 + (wc*64 + n*16 + fr)*32 + fq*8);
#pragma unroll
    for (int m = 0; m < 4; ++m)
#pragma unroll
      for (int n = 0; n < 4; ++n)
        acc[m][n] = __builtin_amdgcn_mfma_f32_16x16x32_bf16(a[m], b[n], acc[m][n], 0, 0, 0);
    __syncthreads();
  }

#pragma unroll
  for (int m = 0; m < 4; ++m) {
#pragma unroll
    for (int n = 0; n < 4; ++n) {
#pragma unroll
      for (int j = 0; j < 4; ++j) {
        long r = m0 + wr*64 + m*16 + fq*4 + j;
        long c = n0 + wc*64 + n*16 + fr;
        float v = acc[m][n][j];
        if (OUT_BF16) ((unsigned short*)Cv)[r * (long)N + c] = f2bf(v);
        else          ((float*)Cv)[r * (long)N + c] = v;
      }
    }
  }
}

// ---------------- YaRN RoPE in-place on fused QKV buffer (stride 6144) ----------------
__global__ __launch_bounds__(256) void rope_fused(unsigned short* __restrict__ C,
                                                  const float* __restrict__ cosb,
                                                  const float* __restrict__ sinb) {
  int idx = blockIdx.x * 256 + threadIdx.x;
  int i = idx & 63;
  int t = idx >> 6;       // s*40 + hh
  int hh = t % 40;
  int s = t / 40;
  const bool isQ = hh < 32;
  unsigned short* row = C + (size_t)s * NQKV + (isQ ? hh * DH : 4096 + (hh - 32) * DH);
  float sc = isQ ? SCALE : 1.0f;
  float c  = cosb[s * DH + i];
  float sn = sinb[s * DH + i];
  float x1 = bf2f(row[i]);
  float x2 = bf2f(row[i + 64]);
  row[i]      = f2bf((x1 * c - x2 * sn) * sc);
  row[i + 64] = f2bf((x2 * c + x1 * sn) * sc);
}

// ---------------- V transpose: C[s][5120+e] -> VT[kvh][d][s] ----------------
__global__ __launch_bounds__(256) void transpose_v(const unsigned short* __restrict__ Vbuf,
                                                   unsigned short* __restrict__ VT) {
  __shared__ unsigned short t[64][72];
  const int s0 = blockIdx.x * 64, e0 = blockIdx.y * 64;
  const int r = threadIdx.x >> 3, c = (threadIdx.x & 7) * 8;
#pragma unroll
  for (int half = 0; half < 2; ++half) {
    int row = r + half * 32;
    *reinterpret_cast<short8*>(&t[row][c]) =
        *reinterpret_cast<const short8*>(Vbuf + (size_t)(s0 + row) * NQKV + e0 + c);
  }
  __syncthreads();
  const int hh = e0 >> 7, dbase = e0 & 127;
#pragma unroll
  for (int half = 0; half < 2; ++half) {
    int row = r + half * 32;
    short8 o;
#pragma unroll
    for (int j = 0; j < 8; ++j) ((unsigned short*)&o)[j] = t[c + j][row];
    *reinterpret_cast<short8*>(VT + (size_t)hh * (DH * (size_t)S_LEN)
                               + (size_t)(dbase + row) * S_LEN + s0 + c) = o;
  }
}

// ---------------- GQA causal flash attention ----------------
// Block = 4 waves = 4 q-heads of one kv-group; K/V staged once, consumed 4x.
// Wave handles strips p and 127-p (uniform 65 strip-tiles). KVBLK=32.
// Per-buffer layout: K[32][128] swz @0 (8 KB), V^T[128][32] swz @8 KB  (16 KB/buf).
// 2-phase dbuf staging, one vmcnt(0)+barrier per tile.
__global__ __launch_bounds__(256) void attn_fwd(const unsigned short* __restrict__ C,
                                                const unsigned short* __restrict__ VT,
                                                unsigned short* __restrict__ Ob) {
  __shared__ unsigned short KVs[2][8192];   // 16 KB per buffer
  __shared__ unsigned short Pl[4][16 * 40]; // per-wave P [16][40], cols 0..31
  const int tid = threadIdx.x, lane = tid & 63, wave = tid >> 6;
  const int kvh = blockIdx.x & 7;
  const int p = blockIdx.x >> 3;             // 0..63
  const int h = kvh * 4 + wave;
  const int fr = lane & 15, fq = lane >> 4;
  const int q0s[2] = { p * 16, (127 - p) * 16 };
  const int tilesA = (p * 16 + 47) >> 5;
  const int tilesB = ((127 - p) * 16 + 47) >> 5;

  const unsigned short* Qbase = C + (size_t)h * DH;
  const unsigned short* Kbase = C + 4096 + (size_t)kvh * DH;
  const unsigned short* Vbase = VT + (size_t)kvh * (DH * (size_t)S_LEN);

  short8 qf[2][4];
#pragma unroll
  for (int s = 0; s < 2; ++s)
#pragma unroll
    for (int dc = 0; dc < 4; ++dc)
      qf[s][dc] = *reinterpret_cast<const short8*>(
          Qbase + (size_t)(q0s[s] + fr) * NQKV + dc * 32 + fq * 8);

  f32x4 o_acc[2][8] = {};
  float mrow[2][4] = {{-1e30f,-1e30f,-1e30f,-1e30f},{-1e30f,-1e30f,-1e30f,-1e30f}};
  float lpart[2][4] = {};

  auto STAGE = [&](int t, int buf) {
    const int kv0 = t * 32;
    char* dst = (char*)&KVs[buf][0];
#pragma unroll
    for (int sh = 0; sh < 2; ++sh) {
      int b = sh * 4096 + tid * 16;
      int krow = b >> 8;
      int kcol = (b & 255) ^ ((krow & 7) << 4);
      __builtin_amdgcn_global_load_lds(
          (const __attribute__((address_space(1))) void*)(Kbase + (size_t)(kv0 + krow) * NQKV + (kcol >> 1)),
          (__attribute__((address_space(3))) void*)(dst + b), 16, 0, 0);
      int vrow = b >> 6;
      int vcol = (b & 63) ^ ((((vrow ^ (vrow >> 2)) & 3)) << 4);
      __builtin_amdgcn_global_load_lds(
          (const __attribute__((address_space(1))) void*)(Vbase + (size_t)vrow * S_LEN + kv0 + (vcol >> 1)),
          (__attribute__((address_space(3))) void*)(dst + 8192 + b), 16, 0, 0);
    }
  };

  int cur = 0;
  STAGE(0, 0);
  asm volatile("s_waitcnt vmcnt(0)" ::: "memory");
  __syncthreads();

  for (int t = 0; t < tilesB; ++t) {
    const int kv0 = t * 32;
    if (t + 1 < tilesB) STAGE(t + 1, cur ^ 1);
    const char* kvb = (const char*)&KVs[cur][0];

#pragma unroll
    for (int s = 0; s < 2; ++s) {
      if (s == 0 && t >= tilesA) continue;
      const int q0 = q0s[s];

      // ---- QK^T: S[16 q][32 kv] from swizzled K LDS ----
      f32x4 sacc[2] = {};
#pragma unroll
      for (int nt = 0; nt < 2; ++nt) {
        const int row = nt * 16 + fr;
#pragma unroll
        for (int dc = 0; dc < 4; ++dc) {
          short8 kf = *reinterpret_cast<const short8*>(
              kvb + row * 256 + ((dc * 64 + fq * 16) ^ ((row & 7) << 4)));
          sacc[nt] = __builtin_amdgcn_mfma_f32_16x16x32_bf16(qf[s][dc], kf, sacc[nt], 0, 0, 0);
        }
      }

      // ---- online softmax: T13 defer-max (no shfl on common path) ----
      const bool needMask = (kv0 + 32 > q0);
      if (needMask) {
#pragma unroll
        for (int j = 0; j < 4; ++j) {
          int qrow = q0 + fq * 4 + j;
#pragma unroll
          for (int nt = 0; nt < 2; ++nt)
            sacc[nt][j] = ((kv0 + nt*16 + fr) <= qrow) ? sacc[nt][j] : -1e30f;
        }
      }
      bool ok = true;
      float lm[4];
#pragma unroll
      for (int j = 0; j < 4; ++j) {
        lm[j] = fmaxf(sacc[0][j], sacc[1][j]);
        ok = ok && (lm[j] <= mrow[s][j] + 8.f);
      }
      if (!__all(ok)) {          // rare: true rescale with full row max
#pragma unroll
        for (int j = 0; j < 4; ++j) {
          float rm = lm[j];
          rm = fmaxf(rm, __shfl_xor(rm, 1));
          rm = fmaxf(rm, __shfl_xor(rm, 2));
          rm = fmaxf(rm, __shfl_xor(rm, 4));
          rm = fmaxf(rm, __shfl_xor(rm, 8));
          float mnew = fmaxf(mrow[s][j], rm);
          float corr = __expf(mrow[s][j] - mnew);
          mrow[s][j] = mnew;
          lpart[s][j] *= corr;
#pragma unroll
          for (int dt = 0; dt < 8; ++dt) o_acc[s][dt][j] *= corr;
        }
      }
#pragma unroll
      for (int j = 0; j < 4; ++j) {
        float p0 = __expf(sacc[0][j] - mrow[s][j]);   // masked -> 0; bounded by e^8
        float p1 = __expf(sacc[1][j] - mrow[s][j]);
        lpart[s][j] += p0 + p1;
        unsigned int u;
        asm("v_cvt_pk_bf16_f32 %0, %1, %2" : "=v"(u) : "v"(p0), "v"(p1));
        Pl[wave][(fq*4 + j)*40 + fr]      = (unsigned short)u;
        Pl[wave][(fq*4 + j)*40 + 16 + fr] = (unsigned short)(u >> 16);
      }
      asm volatile("s_waitcnt lgkmcnt(0)" ::: "memory");
      __builtin_amdgcn_sched_barrier(0);

      // ---- PV: O += P[16 q][32 kv] * V[32 kv][128 d] from swizzled V LDS ----
      short8 pa = *reinterpret_cast<const short8*>(&Pl[wave][fr*40 + fq*8]);
#pragma unroll
      for (int dt = 0; dt < 8; ++dt) {
        const int row = dt * 16 + fr;
        short8 bv = *reinterpret_cast<const short8*>(
            kvb + 8192 + row * 64 + ((fq * 16) ^ ((((row ^ (row >> 2)) & 3)) << 4)));
        o_acc[s][dt] = __builtin_amdgcn_mfma_f32_16x16x32_bf16(pa, bv, o_acc[s][dt], 0, 0, 0);
      }
    }

    asm volatile("s_waitcnt vmcnt(0)" ::: "memory");
    __syncthreads();
    cur ^= 1;
  }

  // epilogue: reduce row sums across fr lanes, normalize, store both strips
#pragma unroll
  for (int s = 0; s < 2; ++s)
#pragma unroll
    for (int j = 0; j < 4; ++j) {
      float l = lpart[s][j];
      l += __shfl_xor(l, 1);
      l += __shfl_xor(l, 2);
      l += __shfl_xor(l, 4);
      l += __shfl_xor(l, 8);
      float inv = 1.f / l;
      size_t r = (size_t)q0s[s] + fq*4 + j;
#pragma unroll
      for (int dt = 0; dt < 8; ++dt)
        Ob[r * QDIM + h * DH + dt*16 + fr] = f2bf(o_acc[s][dt][j] * inv);
    }
}

// ---------------- launch ----------------
extern "C" void kernel_launch(void* const* d_in, const int* in_sizes, int n_in,
                              void* d_out, int out_size, void* d_ws, size_t ws_size,
                              hipStream_t stream) {
  (void)in_sizes; (void)n_in; (void)out_size; (void)ws_size;
  const float* x    = (const float*)d_in[0];
  const float* Wq   = (const float*)d_in[1];
  const float* Wk   = (const float*)d_in[2];
  const float* Wv   = (const float*)d_in[3];
  const float* Wo   = (const float*)d_in[4];
  const float* cosb = (const float*)d_in[5];
  const float* sinb = (const float*)d_in[6];

  char* ws = (char*)d_ws;
  unsigned short* xb    = (unsigned short*)(ws);               // 16.8 MB (dead after QKV gemm)
  unsigned short* Wqkvb = (unsigned short*)(ws + 16777216);    // 50.3 MB [Wq;Wk;Wv]
  unsigned short* Wob   = (unsigned short*)(ws + 67108864);    // 33.6 MB
  unsigned short* Cqkv  = (unsigned short*)(ws + 100663296);   // 25.2 MB [Q|K|V] stride 6144
  unsigned short* VT    = (unsigned short*)(ws + 125829120);   // 4.2 MB
  unsigned short* Ab    = xb;                                  // reuse

  cvt_all<<<49152, 256, 0, stream>>>(x, Wq, Wk, Wv, Wo, xb, Wqkvb, Wob);

  gemm_bt<1><<<dim3(48, 16), 256, 0, stream>>>(xb, Wqkvb, Cqkv, 2048, NQKV, 4096);

  rope_fused<<<20480, 256, 0, stream>>>(Cqkv, cosb, sinb);
  transpose_v<<<dim3(32, 16), 256, 0, stream>>>(Cqkv + 5120, VT);

  attn_fwd<<<512, 256, 0, stream>>>(Cqkv, VT, Ab);

  gemm_bt<0><<<dim3(32, 16), 256, 0, stream>>>(Ab, Wob, d_out, 2048, 4096, 4096);
}

// Round 7
// 321.684 us; speedup vs baseline: 2.7280x; 1.2217x over previous
//
#include <hip/hip_runtime.h>

#define S_LEN 2048
#define DMODEL 4096
#define NH 32
#define NKV 8
#define DH 128
#define QDIM (NH*DH)      // 4096
#define NQKV 6144         // fused projection width
#define SCALE 0.08838834764831845f

typedef __attribute__((ext_vector_type(8))) short short8;
typedef __attribute__((ext_vector_type(4))) float f32x4;
typedef __attribute__((ext_vector_type(4))) unsigned short us4;

__device__ __forceinline__ unsigned short f2bf(float f) {
  union { float f; unsigned int u; } v; v.f = f;
  unsigned int r = v.u + 0x7FFFu + ((v.u >> 16) & 1u);
  return (unsigned short)(r >> 16);
}
__device__ __forceinline__ float bf2f(unsigned short h) {
  union { unsigned int u; float f; } v; v.u = ((unsigned int)h) << 16;
  return v.f;
}

// ---------------- fused f32 -> bf16 convert for all 5 tensors ----------------
__global__ __launch_bounds__(256) void cvt_all(const float* __restrict__ x,
                                               const float* __restrict__ Wq,
                                               const float* __restrict__ Wk,
                                               const float* __restrict__ Wv,
                                               const float* __restrict__ Wo,
                                               unsigned short* __restrict__ xb,
                                               unsigned short* __restrict__ Wqkvb,
                                               unsigned short* __restrict__ Wob) {
  const int blk = blockIdx.x;
  const float* src; unsigned short* dst; int off;
  if (blk < 8192)       { src = x;  dst = xb;               off = blk; }
  else if (blk < 24576) { src = Wq; dst = Wqkvb;            off = blk - 8192; }
  else if (blk < 28672) { src = Wk; dst = Wqkvb + 16777216; off = blk - 24576; }
  else if (blk < 32768) { src = Wv; dst = Wqkvb + 20971520; off = blk - 28672; }
  else                  { src = Wo; dst = Wob;              off = blk - 32768; }
  int i = off * 256 + threadIdx.x;
  const float4 f = reinterpret_cast<const float4*>(src)[i];
  us4 o;
  o.x = f2bf(f.x); o.y = f2bf(f.y); o.z = f2bf(f.z); o.w = f2bf(f.w);
  reinterpret_cast<us4*>(dst)[i] = o;
}

// ---------------- 256x(BN) 8-phase GEMM: C[M,N] = A[M,K] * B[N,K]^T ----------------
// 512 thr = 8 waves (2M x 4N). BK=64. Per-wave out: 128 x BN/4.
// Per K-tile: ph1{12 ds_read, bar, MFMA q0, bar} ph2{12 ds_read, bar, MFMA q1, bar}
//             ph3{stage A(t+2), MFMA q2, bar} ph4{stage B(t+2), MFMA q3, vmcnt(LPT), bar}
// Raw s_barrier (no vmcnt drain); LDS rows XOR-swizzled by ((row&7)<<4) on both sides.
// Race-free: all buf-c ds_reads complete before ph2-end barrier; t+2 stages issue after it.
template<int M_, int N_, int K_, int BN_, int OUT_BF16, int CHN>
__global__ __launch_bounds__(512) void gemm8p(const unsigned short* __restrict__ A,
                                              const unsigned short* __restrict__ B,
                                              void* __restrict__ Cv) {
  constexpr int ATILE = 32768;           // 256 x 64 x 2B
  constexpr int BTILE = BN_ * 128;       // BN x 64 x 2B
  constexpr int BUF = ATILE + BTILE;
  constexpr int LPTB = BN_ / 64;         // B stage loads/thread (4 or 2)
  constexpr int NF = BN_ / 64;           // n-frags per wave (4 or 2)
  constexpr int NT = K_ / 64;
  __shared__ char lds[2 * BUF];

  const int tid = threadIdx.x;
  const int lane = tid & 63, wave = tid >> 6;
  const int wm = wave >> 2, wn = wave & 3;
  const int fr = lane & 15, fq = lane >> 4;

  // bijective XCD-chunked remap: XCD k owns n-tile chunk [k*CHN, k*CHN+CHN) x all m
  const int lin = blockIdx.x;
  const int xcd = lin & 7;
  const int slot = lin >> 3;
  const long n0 = (long)(xcd * CHN + slot % CHN) * BN_;
  const long m0 = (long)(slot / CHN) * 256;

  auto STAGE_A = [&](int t, int c) {
#pragma unroll
    for (int u = 0; u < 4; ++u) {
      int b = u * 8192 + tid * 16;
      int row = b >> 7;
      int off = (b & 127) ^ ((row & 7) << 4);
      __builtin_amdgcn_global_load_lds(
        (const __attribute__((address_space(1))) void*)((const char*)A + ((m0 + row) * (long)K_ + t * 64) * 2 + off),
        (__attribute__((address_space(3))) void*)(lds + c * BUF + b), 16, 0, 0);
    }
  };
  auto STAGE_B = [&](int t, int c) {
#pragma unroll
    for (int u = 0; u < LPTB; ++u) {
      int b = u * 8192 + tid * 16;
      int row = b >> 7;
      int off = (b & 127) ^ ((row & 7) << 4);
      __builtin_amdgcn_global_load_lds(
        (const __attribute__((address_space(1))) void*)((const char*)B + ((n0 + row) * (long)K_ + t * 64) * 2 + off),
        (__attribute__((address_space(3))) void*)(lds + c * BUF + ATILE + b), 16, 0, 0);
    }
  };
#define VMCNT_STEADY() do { if constexpr (BN_ == 256) asm volatile("s_waitcnt vmcnt(8)" ::: "memory"); \
                            else                      asm volatile("s_waitcnt vmcnt(6)" ::: "memory"); } while (0)

  f32x4 acc[8][NF] = {};
  short8 af[8][2];
  short8 bf[NF][2];

  STAGE_A(0, 0); STAGE_B(0, 0);
  STAGE_A(1, 1); STAGE_B(1, 1);
  VMCNT_STEADY();
  __builtin_amdgcn_s_barrier();

  for (int t = 0; t < NT; ++t) {
    const int c = t & 1;
    const char* tb = lds + c * BUF;

    // ---- ph1: read af[0..3], bf[0..NF/2) ----
#pragma unroll
    for (int mi = 0; mi < 4; ++mi) {
      int row = wm * 128 + mi * 16 + fr;
#pragma unroll
      for (int ks = 0; ks < 2; ++ks)
        af[mi][ks] = *(const short8*)(tb + row * 128 + ((ks * 64 + fq * 16) ^ ((row & 7) << 4)));
    }
#pragma unroll
    for (int ni = 0; ni < NF / 2; ++ni) {
      int row = wn * (BN_ / 4) + ni * 16 + fr;
#pragma unroll
      for (int ks = 0; ks < 2; ++ks)
        bf[ni][ks] = *(const short8*)(tb + ATILE + row * 128 + ((ks * 64 + fq * 16) ^ ((row & 7) << 4)));
    }
    __builtin_amdgcn_s_barrier();
    __builtin_amdgcn_s_setprio(1);
#pragma unroll
    for (int mi = 0; mi < 4; ++mi)
#pragma unroll
      for (int ni = 0; ni < NF / 2; ++ni)
#pragma unroll
        for (int ks = 0; ks < 2; ++ks)
          acc[mi][ni] = __builtin_amdgcn_mfma_f32_16x16x32_bf16(af[mi][ks], bf[ni][ks], acc[mi][ni], 0, 0, 0);
    __builtin_amdgcn_s_setprio(0);
    __builtin_amdgcn_s_barrier();

    // ---- ph2: read af[4..7], bf[NF/2..NF) ----
#pragma unroll
    for (int mi = 4; mi < 8; ++mi) {
      int row = wm * 128 + mi * 16 + fr;
#pragma unroll
      for (int ks = 0; ks < 2; ++ks)
        af[mi][ks] = *(const short8*)(tb + row * 128 + ((ks * 64 + fq * 16) ^ ((row & 7) << 4)));
    }
#pragma unroll
    for (int ni = NF / 2; ni < NF; ++ni) {
      int row = wn * (BN_ / 4) + ni * 16 + fr;
#pragma unroll
      for (int ks = 0; ks < 2; ++ks)
        bf[ni][ks] = *(const short8*)(tb + ATILE + row * 128 + ((ks * 64 + fq * 16) ^ ((row & 7) << 4)));
    }
    __builtin_amdgcn_s_barrier();
    __builtin_amdgcn_s_setprio(1);
#pragma unroll
    for (int mi = 0; mi < 4; ++mi)
#pragma unroll
      for (int ni = NF / 2; ni < NF; ++ni)
#pragma unroll
        for (int ks = 0; ks < 2; ++ks)
          acc[mi][ni] = __builtin_amdgcn_mfma_f32_16x16x32_bf16(af[mi][ks], bf[ni][ks], acc[mi][ni], 0, 0, 0);
    __builtin_amdgcn_s_setprio(0);
    __builtin_amdgcn_s_barrier();

    // ---- ph3: stage A(t+2) into buf c (reads of buf c all done); MFMA q2 ----
    if (t + 2 < NT) STAGE_A(t + 2, c);
    __builtin_amdgcn_s_setprio(1);
#pragma unroll
    for (int mi = 4; mi < 8; ++mi)
#pragma unroll
      for (int ni = 0; ni < NF / 2; ++ni)
#pragma unroll
        for (int ks = 0; ks < 2; ++ks)
          acc[mi][ni] = __builtin_amdgcn_mfma_f32_16x16x32_bf16(af[mi][ks], bf[ni][ks], acc[mi][ni], 0, 0, 0);
    __builtin_amdgcn_s_setprio(0);
    __builtin_amdgcn_s_barrier();

    // ---- ph4: stage B(t+2); MFMA q3; counted vmcnt; barrier ----
    if (t + 2 < NT) STAGE_B(t + 2, c);
    __builtin_amdgcn_s_setprio(1);
#pragma unroll
    for (int mi = 4; mi < 8; ++mi)
#pragma unroll
      for (int ni = NF / 2; ni < NF; ++ni)
#pragma unroll
        for (int ks = 0; ks < 2; ++ks)
          acc[mi][ni] = __builtin_amdgcn_mfma_f32_16x16x32_bf16(af[mi][ks], bf[ni][ks], acc[mi][ni], 0, 0, 0);
    __builtin_amdgcn_s_setprio(0);
    if (t + 2 < NT) { VMCNT_STEADY(); }
    else if (t + 1 < NT) { asm volatile("s_waitcnt vmcnt(0)" ::: "memory"); }
    __builtin_amdgcn_s_barrier();
  }
#undef VMCNT_STEADY

  // epilogue
#pragma unroll
  for (int mi = 0; mi < 8; ++mi)
#pragma unroll
    for (int ni = 0; ni < NF; ++ni)
#pragma unroll
      for (int j = 0; j < 4; ++j) {
        long r = m0 + wm * 128 + mi * 16 + fq * 4 + j;
        long cc = n0 + wn * (BN_ / 4) + ni * 16 + fr;
        float v = acc[mi][ni][j];
        if (OUT_BF16) ((unsigned short*)Cv)[r * N_ + cc] = f2bf(v);
        else          ((float*)Cv)[r * N_ + cc] = v;
      }
}

// ---------------- YaRN RoPE in-place on fused QKV buffer (stride 6144) ----------------
__global__ __launch_bounds__(256) void rope_fused(unsigned short* __restrict__ C,
                                                  const float* __restrict__ cosb,
                                                  const float* __restrict__ sinb) {
  int idx = blockIdx.x * 256 + threadIdx.x;
  int i = idx & 63;
  int t = idx >> 6;       // s*40 + hh
  int hh = t % 40;
  int s = t / 40;
  const bool isQ = hh < 32;
  unsigned short* row = C + (size_t)s * NQKV + (isQ ? hh * DH : 4096 + (hh - 32) * DH);
  float sc = isQ ? SCALE : 1.0f;
  float c  = cosb[s * DH + i];
  float sn = sinb[s * DH + i];
  float x1 = bf2f(row[i]);
  float x2 = bf2f(row[i + 64]);
  row[i]      = f2bf((x1 * c - x2 * sn) * sc);
  row[i + 64] = f2bf((x2 * c + x1 * sn) * sc);
}

// ---------------- V transpose: C[s][5120+e] -> VT[kvh][d][s] ----------------
__global__ __launch_bounds__(256) void transpose_v(const unsigned short* __restrict__ Vbuf,
                                                   unsigned short* __restrict__ VT) {
  __shared__ unsigned short t[64][72];
  const int s0 = blockIdx.x * 64, e0 = blockIdx.y * 64;
  const int r = threadIdx.x >> 3, c = (threadIdx.x & 7) * 8;
#pragma unroll
  for (int half = 0; half < 2; ++half) {
    int row = r + half * 32;
    *reinterpret_cast<short8*>(&t[row][c]) =
        *reinterpret_cast<const short8*>(Vbuf + (size_t)(s0 + row) * NQKV + e0 + c);
  }
  __syncthreads();
  const int hh = e0 >> 7, dbase = e0 & 127;
#pragma unroll
  for (int half = 0; half < 2; ++half) {
    int row = r + half * 32;
    short8 o;
#pragma unroll
    for (int j = 0; j < 8; ++j) ((unsigned short*)&o)[j] = t[c + j][row];
    *reinterpret_cast<short8*>(VT + (size_t)hh * (DH * (size_t)S_LEN)
                               + (size_t)(dbase + row) * S_LEN + s0 + c) = o;
  }
}

// ---------------- GQA causal flash attention (round-6, unchanged) ----------------
__global__ __launch_bounds__(256) void attn_fwd(const unsigned short* __restrict__ C,
                                                const unsigned short* __restrict__ VT,
                                                unsigned short* __restrict__ Ob) {
  __shared__ unsigned short KVs[2][8192];   // 16 KB per buffer: K[32][128] swz @0, V^T[128][32] swz @8KB
  __shared__ unsigned short Pl[4][16 * 40];
  const int tid = threadIdx.x, lane = tid & 63, wave = tid >> 6;
  const int kvh = blockIdx.x & 7;
  const int p = blockIdx.x >> 3;
  const int h = kvh * 4 + wave;
  const int fr = lane & 15, fq = lane >> 4;
  const int q0s[2] = { p * 16, (127 - p) * 16 };
  const int tilesA = (p * 16 + 47) >> 5;
  const int tilesB = ((127 - p) * 16 + 47) >> 5;

  const unsigned short* Qbase = C + (size_t)h * DH;
  const unsigned short* Kbase = C + 4096 + (size_t)kvh * DH;
  const unsigned short* Vbase = VT + (size_t)kvh * (DH * (size_t)S_LEN);

  short8 qf[2][4];
#pragma unroll
  for (int s = 0; s < 2; ++s)
#pragma unroll
    for (int dc = 0; dc < 4; ++dc)
      qf[s][dc] = *reinterpret_cast<const short8*>(
          Qbase + (size_t)(q0s[s] + fr) * NQKV + dc * 32 + fq * 8);

  f32x4 o_acc[2][8] = {};
  float mrow[2][4] = {{-1e30f,-1e30f,-1e30f,-1e30f},{-1e30f,-1e30f,-1e30f,-1e30f}};
  float lpart[2][4] = {};

  auto STAGE = [&](int t, int buf) {
    const int kv0 = t * 32;
    char* dst = (char*)&KVs[buf][0];
#pragma unroll
    for (int sh = 0; sh < 2; ++sh) {
      int b = sh * 4096 + tid * 16;
      int krow = b >> 8;
      int kcol = (b & 255) ^ ((krow & 7) << 4);
      __builtin_amdgcn_global_load_lds(
          (const __attribute__((address_space(1))) void*)(Kbase + (size_t)(kv0 + krow) * NQKV + (kcol >> 1)),
          (__attribute__((address_space(3))) void*)(dst + b), 16, 0, 0);
      int vrow = b >> 6;
      int vcol = (b & 63) ^ ((((vrow ^ (vrow >> 2)) & 3)) << 4);
      __builtin_amdgcn_global_load_lds(
          (const __attribute__((address_space(1))) void*)(Vbase + (size_t)vrow * S_LEN + kv0 + (vcol >> 1)),
          (__attribute__((address_space(3))) void*)(dst + 8192 + b), 16, 0, 0);
    }
  };

  int cur = 0;
  STAGE(0, 0);
  asm volatile("s_waitcnt vmcnt(0)" ::: "memory");
  __syncthreads();

  for (int t = 0; t < tilesB; ++t) {
    const int kv0 = t * 32;
    if (t + 1 < tilesB) STAGE(t + 1, cur ^ 1);
    const char* kvb = (const char*)&KVs[cur][0];

#pragma unroll
    for (int s = 0; s < 2; ++s) {
      if (s == 0 && t >= tilesA) continue;
      const int q0 = q0s[s];

      f32x4 sacc[2] = {};
#pragma unroll
      for (int nt = 0; nt < 2; ++nt) {
        const int row = nt * 16 + fr;
#pragma unroll
        for (int dc = 0; dc < 4; ++dc) {
          short8 kf = *reinterpret_cast<const short8*>(
              kvb + row * 256 + ((dc * 64 + fq * 16) ^ ((row & 7) << 4)));
          sacc[nt] = __builtin_amdgcn_mfma_f32_16x16x32_bf16(qf[s][dc], kf, sacc[nt], 0, 0, 0);
        }
      }

      const bool needMask = (kv0 + 32 > q0);
      if (needMask) {
#pragma unroll
        for (int j = 0; j < 4; ++j) {
          int qrow = q0 + fq * 4 + j;
#pragma unroll
          for (int nt = 0; nt < 2; ++nt)
            sacc[nt][j] = ((kv0 + nt*16 + fr) <= qrow) ? sacc[nt][j] : -1e30f;
        }
      }
      bool ok = true;
      float lm[4];
#pragma unroll
      for (int j = 0; j < 4; ++j) {
        lm[j] = fmaxf(sacc[0][j], sacc[1][j]);
        ok = ok && (lm[j] <= mrow[s][j] + 8.f);
      }
      if (!__all(ok)) {
#pragma unroll
        for (int j = 0; j < 4; ++j) {
          float rm = lm[j];
          rm = fmaxf(rm, __shfl_xor(rm, 1));
          rm = fmaxf(rm, __shfl_xor(rm, 2));
          rm = fmaxf(rm, __shfl_xor(rm, 4));
          rm = fmaxf(rm, __shfl_xor(rm, 8));
          float mnew = fmaxf(mrow[s][j], rm);
          float corr = __expf(mrow[s][j] - mnew);
          mrow[s][j] = mnew;
          lpart[s][j] *= corr;
#pragma unroll
          for (int dt = 0; dt < 8; ++dt) o_acc[s][dt][j] *= corr;
        }
      }
#pragma unroll
      for (int j = 0; j < 4; ++j) {
        float p0 = __expf(sacc[0][j] - mrow[s][j]);
        float p1 = __expf(sacc[1][j] - mrow[s][j]);
        lpart[s][j] += p0 + p1;
        unsigned int u;
        asm("v_cvt_pk_bf16_f32 %0, %1, %2" : "=v"(u) : "v"(p0), "v"(p1));
        Pl[wave][(fq*4 + j)*40 + fr]      = (unsigned short)u;
        Pl[wave][(fq*4 + j)*40 + 16 + fr] = (unsigned short)(u >> 16);
      }
      asm volatile("s_waitcnt lgkmcnt(0)" ::: "memory");
      __builtin_amdgcn_sched_barrier(0);

      short8 pa = *reinterpret_cast<const short8*>(&Pl[wave][fr*40 + fq*8]);
#pragma unroll
      for (int dt = 0; dt < 8; ++dt) {
        const int row = dt * 16 + fr;
        short8 bv = *reinterpret_cast<const short8*>(
            kvb + 8192 + row * 64 + ((fq * 16) ^ ((((row ^ (row >> 2)) & 3)) << 4)));
        o_acc[s][dt] = __builtin_amdgcn_mfma_f32_16x16x32_bf16(pa, bv, o_acc[s][dt], 0, 0, 0);
      }
    }

    asm volatile("s_waitcnt vmcnt(0)" ::: "memory");
    __syncthreads();
    cur ^= 1;
  }

#pragma unroll
  for (int s = 0; s < 2; ++s)
#pragma unroll
    for (int j = 0; j < 4; ++j) {
      float l = lpart[s][j];
      l += __shfl_xor(l, 1);
      l += __shfl_xor(l, 2);
      l += __shfl_xor(l, 4);
      l += __shfl_xor(l, 8);
      float inv = 1.f / l;
      size_t r = (size_t)q0s[s] + fq*4 + j;
#pragma unroll
      for (int dt = 0; dt < 8; ++dt)
        Ob[r * QDIM + h * DH + dt*16 + fr] = f2bf(o_acc[s][dt][j] * inv);
    }
}

// ---------------- launch ----------------
extern "C" void kernel_launch(void* const* d_in, const int* in_sizes, int n_in,
                              void* d_out, int out_size, void* d_ws, size_t ws_size,
                              hipStream_t stream) {
  (void)in_sizes; (void)n_in; (void)out_size; (void)ws_size;
  const float* x    = (const float*)d_in[0];
  const float* Wq   = (const float*)d_in[1];
  const float* Wk   = (const float*)d_in[2];
  const float* Wv   = (const float*)d_in[3];
  const float* Wo   = (const float*)d_in[4];
  const float* cosb = (const float*)d_in[5];
  const float* sinb = (const float*)d_in[6];

  char* ws = (char*)d_ws;
  unsigned short* xb    = (unsigned short*)(ws);               // 16.8 MB (dead after QKV gemm)
  unsigned short* Wqkvb = (unsigned short*)(ws + 16777216);    // 50.3 MB [Wq;Wk;Wv]
  unsigned short* Wob   = (unsigned short*)(ws + 67108864);    // 33.6 MB
  unsigned short* Cqkv  = (unsigned short*)(ws + 100663296);   // 25.2 MB [Q|K|V] stride 6144
  unsigned short* VT    = (unsigned short*)(ws + 125829120);   // 4.2 MB
  unsigned short* Ab    = xb;                                  // reuse

  cvt_all<<<49152, 256, 0, stream>>>(x, Wq, Wk, Wv, Wo, xb, Wqkvb, Wob);

  // QKV projection: M=2048, N=6144, BN=256 -> 192 blocks, CHN=3 n-tiles/XCD
  gemm8p<2048, 6144, 4096, 256, 1, 3><<<192, 512, 0, stream>>>(xb, Wqkvb, Cqkv);

  rope_fused<<<20480, 256, 0, stream>>>(Cqkv, cosb, sinb);
  transpose_v<<<dim3(32, 16), 256, 0, stream>>>(Cqkv + 5120, VT);

  attn_fwd<<<512, 256, 0, stream>>>(Cqkv, VT, Ab);

  // Output projection: M=2048, N=4096, BN=128 -> 256 blocks (full chip), CHN=4
  gemm8p<2048, 4096, 4096, 128, 0, 4><<<256, 512, 0, stream>>>(Ab, Wob, d_out);
}

// Round 8
// 306.184 us; speedup vs baseline: 2.8661x; 1.0506x over previous
//
#include <hip/hip_runtime.h>

#define S_LEN 2048
#define DMODEL 4096
#define NH 32
#define NKV 8
#define DH 128
#define QDIM (NH*DH)      // 4096
#define NQKV 6144         // fused projection width
#define SCALE 0.08838834764831845f

typedef __attribute__((ext_vector_type(8))) short short8;
typedef __attribute__((ext_vector_type(4))) float f32x4;
typedef __attribute__((ext_vector_type(4))) unsigned short us4;

__device__ __forceinline__ unsigned short f2bf(float f) {
  union { float f; unsigned int u; } v; v.f = f;
  unsigned int r = v.u + 0x7FFFu + ((v.u >> 16) & 1u);
  return (unsigned short)(r >> 16);
}
__device__ __forceinline__ float bf2f(unsigned short h) {
  union { unsigned int u; float f; } v; v.u = ((unsigned int)h) << 16;
  return v.f;
}

// ---------------- fused f32 -> bf16 convert for all 5 tensors ----------------
__global__ __launch_bounds__(256) void cvt_all(const float* __restrict__ x,
                                               const float* __restrict__ Wq,
                                               const float* __restrict__ Wk,
                                               const float* __restrict__ Wv,
                                               const float* __restrict__ Wo,
                                               unsigned short* __restrict__ xb,
                                               unsigned short* __restrict__ Wqkvb,
                                               unsigned short* __restrict__ Wob) {
  const int blk = blockIdx.x;
  const float* src; unsigned short* dst; int off;
  if (blk < 8192)       { src = x;  dst = xb;               off = blk; }
  else if (blk < 24576) { src = Wq; dst = Wqkvb;            off = blk - 8192; }
  else if (blk < 28672) { src = Wk; dst = Wqkvb + 16777216; off = blk - 24576; }
  else if (blk < 32768) { src = Wv; dst = Wqkvb + 20971520; off = blk - 28672; }
  else                  { src = Wo; dst = Wob;              off = blk - 32768; }
  int i = off * 256 + threadIdx.x;
  const float4 f = reinterpret_cast<const float4*>(src)[i];
  us4 o;
  o.x = f2bf(f.x); o.y = f2bf(f.y); o.z = f2bf(f.z); o.w = f2bf(f.w);
  reinterpret_cast<us4*>(dst)[i] = o;
}

// ---------------- (BM x BN) 8-phase GEMM: C[M,N] = A[M,K] * B[N,K]^T ----------------
// 512 thr = 8 waves (2M x 4N). BK=64. Per-wave out: (BM/2) x (BN/4).
// Per K-tile: ph1{af-lo+bf-lo reads, bar, MFMA lo*lo, bar} ph2{af-hi+bf-hi reads, bar, MFMA lo*hi, bar}
//             ph3{stage A(t+2), MFMA hi*lo, bar} ph4{stage B(t+2), MFMA hi*hi, vmcnt(VM), bar}
// Raw s_barrier (no vmcnt drain); LDS rows XOR-swizzled by ((row&7)<<4) on both sides.
// Race-free: all buf-c ds_reads complete before ph2-end barrier; t+2 stages issue after it.
template<int M_, int N_, int K_, int BM_, int BN_, int OUT_BF16, int CHN>
__global__ __launch_bounds__(512) void gemm8p(const unsigned short* __restrict__ A,
                                              const unsigned short* __restrict__ B,
                                              void* __restrict__ Cv) {
  constexpr int ATILE = BM_ * 128;       // BM x 64 x 2B
  constexpr int BTILE = BN_ * 128;
  constexpr int BUF = ATILE + BTILE;
  constexpr int LPA = BM_ / 64;          // A stage loads/thread
  constexpr int LPB = BN_ / 64;          // B stage loads/thread
  constexpr int VM  = LPA + LPB;         // in-flight loads per staged tile (per wave)
  constexpr int MI = BM_ / 32;           // m frags per wave
  constexpr int NF = BN_ / 64;           // n frags per wave
  constexpr int MIL = MI / 2;
  constexpr int NFL = NF / 2;            // NF=3 -> 1
  constexpr int NT = K_ / 64;
  __shared__ char lds[2 * BUF];

  const int tid = threadIdx.x;
  const int lane = tid & 63, wave = tid >> 6;
  const int wm = wave >> 2, wn = wave & 3;
  const int fr = lane & 15, fq = lane >> 4;

  // bijective XCD-chunked remap: XCD k owns n-chunk [k*CHN, (k+1)*CHN) x all m-tiles
  const int lin = blockIdx.x;
  const int xcd = lin & 7;
  const int slot = lin >> 3;
  const long n0 = (long)(xcd * CHN + slot % CHN) * BN_;
  const long m0 = (long)(slot / CHN) * BM_;

  auto STAGE_A = [&](int t, int c) {
#pragma unroll
    for (int u = 0; u < LPA; ++u) {
      int b = u * 8192 + tid * 16;
      int row = b >> 7;
      int off = (b & 127) ^ ((row & 7) << 4);
      __builtin_amdgcn_global_load_lds(
        (const __attribute__((address_space(1))) void*)((const char*)A + ((m0 + row) * (long)K_ + t * 64) * 2 + off),
        (__attribute__((address_space(3))) void*)(lds + c * BUF + b), 16, 0, 0);
    }
  };
  auto STAGE_B = [&](int t, int c) {
#pragma unroll
    for (int u = 0; u < LPB; ++u) {
      int b = u * 8192 + tid * 16;
      int row = b >> 7;
      int off = (b & 127) ^ ((row & 7) << 4);
      __builtin_amdgcn_global_load_lds(
        (const __attribute__((address_space(1))) void*)((const char*)B + ((n0 + row) * (long)K_ + t * 64) * 2 + off),
        (__attribute__((address_space(3))) void*)(lds + c * BUF + ATILE + b), 16, 0, 0);
    }
  };
#define VMCNT_STEADY() do { if constexpr (VM == 6) asm volatile("s_waitcnt vmcnt(6)" ::: "memory"); \
                            else if constexpr (VM == 7) asm volatile("s_waitcnt vmcnt(7)" ::: "memory"); \
                            else asm volatile("s_waitcnt vmcnt(8)" ::: "memory"); } while (0)

  f32x4 acc[MI][NF] = {};
  short8 af[MI][2];
  short8 bf[NF][2];

  STAGE_A(0, 0); STAGE_B(0, 0);
  STAGE_A(1, 1); STAGE_B(1, 1);
  VMCNT_STEADY();
  __builtin_amdgcn_s_barrier();

  for (int t = 0; t < NT; ++t) {
    const int c = t & 1;
    const char* tb = lds + c * BUF;

    // ---- ph1: read af-lo, bf-lo; MFMA lo x lo ----
#pragma unroll
    for (int mi = 0; mi < MIL; ++mi) {
      int row = wm * (BM_ / 2) + mi * 16 + fr;
#pragma unroll
      for (int ks = 0; ks < 2; ++ks)
        af[mi][ks] = *(const short8*)(tb + row * 128 + ((ks * 64 + fq * 16) ^ ((row & 7) << 4)));
    }
#pragma unroll
    for (int ni = 0; ni < NFL; ++ni) {
      int row = wn * (BN_ / 4) + ni * 16 + fr;
#pragma unroll
      for (int ks = 0; ks < 2; ++ks)
        bf[ni][ks] = *(const short8*)(tb + ATILE + row * 128 + ((ks * 64 + fq * 16) ^ ((row & 7) << 4)));
    }
    __builtin_amdgcn_s_barrier();
    __builtin_amdgcn_s_setprio(1);
#pragma unroll
    for (int mi = 0; mi < MIL; ++mi)
#pragma unroll
      for (int ni = 0; ni < NFL; ++ni)
#pragma unroll
        for (int ks = 0; ks < 2; ++ks)
          acc[mi][ni] = __builtin_amdgcn_mfma_f32_16x16x32_bf16(af[mi][ks], bf[ni][ks], acc[mi][ni], 0, 0, 0);
    __builtin_amdgcn_s_setprio(0);
    __builtin_amdgcn_s_barrier();

    // ---- ph2: read af-hi, bf-hi; MFMA lo x hi ----
#pragma unroll
    for (int mi = MIL; mi < MI; ++mi) {
      int row = wm * (BM_ / 2) + mi * 16 + fr;
#pragma unroll
      for (int ks = 0; ks < 2; ++ks)
        af[mi][ks] = *(const short8*)(tb + row * 128 + ((ks * 64 + fq * 16) ^ ((row & 7) << 4)));
    }
#pragma unroll
    for (int ni = NFL; ni < NF; ++ni) {
      int row = wn * (BN_ / 4) + ni * 16 + fr;
#pragma unroll
      for (int ks = 0; ks < 2; ++ks)
        bf[ni][ks] = *(const short8*)(tb + ATILE + row * 128 + ((ks * 64 + fq * 16) ^ ((row & 7) << 4)));
    }
    __builtin_amdgcn_s_barrier();
    __builtin_amdgcn_s_setprio(1);
#pragma unroll
    for (int mi = 0; mi < MIL; ++mi)
#pragma unroll
      for (int ni = NFL; ni < NF; ++ni)
#pragma unroll
        for (int ks = 0; ks < 2; ++ks)
          acc[mi][ni] = __builtin_amdgcn_mfma_f32_16x16x32_bf16(af[mi][ks], bf[ni][ks], acc[mi][ni], 0, 0, 0);
    __builtin_amdgcn_s_setprio(0);
    __builtin_amdgcn_s_barrier();

    // ---- ph3: stage A(t+2) into buf c (all buf-c reads done); MFMA hi x lo ----
    if (t + 2 < NT) STAGE_A(t + 2, c);
    __builtin_amdgcn_s_setprio(1);
#pragma unroll
    for (int mi = MIL; mi < MI; ++mi)
#pragma unroll
      for (int ni = 0; ni < NFL; ++ni)
#pragma unroll
        for (int ks = 0; ks < 2; ++ks)
          acc[mi][ni] = __builtin_amdgcn_mfma_f32_16x16x32_bf16(af[mi][ks], bf[ni][ks], acc[mi][ni], 0, 0, 0);
    __builtin_amdgcn_s_setprio(0);
    __builtin_amdgcn_s_barrier();

    // ---- ph4: stage B(t+2); MFMA hi x hi; counted vmcnt; barrier ----
    if (t + 2 < NT) STAGE_B(t + 2, c);
    __builtin_amdgcn_s_setprio(1);
#pragma unroll
    for (int mi = MIL; mi < MI; ++mi)
#pragma unroll
      for (int ni = NFL; ni < NF; ++ni)
#pragma unroll
        for (int ks = 0; ks < 2; ++ks)
          acc[mi][ni] = __builtin_amdgcn_mfma_f32_16x16x32_bf16(af[mi][ks], bf[ni][ks], acc[mi][ni], 0, 0, 0);
    __builtin_amdgcn_s_setprio(0);
    if (t + 2 < NT) { VMCNT_STEADY(); }
    else if (t + 1 < NT) { asm volatile("s_waitcnt vmcnt(0)" ::: "memory"); }
    __builtin_amdgcn_s_barrier();
  }
#undef VMCNT_STEADY

  // epilogue
#pragma unroll
  for (int mi = 0; mi < MI; ++mi)
#pragma unroll
    for (int ni = 0; ni < NF; ++ni)
#pragma unroll
      for (int j = 0; j < 4; ++j) {
        long r = m0 + wm * (BM_ / 2) + mi * 16 + fq * 4 + j;
        long cc = n0 + wn * (BN_ / 4) + ni * 16 + fr;
        float v = acc[mi][ni][j];
        if (OUT_BF16) ((unsigned short*)Cv)[r * N_ + cc] = f2bf(v);
        else          ((float*)Cv)[r * N_ + cc] = v;
      }
}

// ---------------- YaRN RoPE in-place on fused QKV buffer (stride 6144) ----------------
__global__ __launch_bounds__(256) void rope_fused(unsigned short* __restrict__ C,
                                                  const float* __restrict__ cosb,
                                                  const float* __restrict__ sinb) {
  int idx = blockIdx.x * 256 + threadIdx.x;
  int i = idx & 63;
  int t = idx >> 6;       // s*40 + hh
  int hh = t % 40;
  int s = t / 40;
  const bool isQ = hh < 32;
  unsigned short* row = C + (size_t)s * NQKV + (isQ ? hh * DH : 4096 + (hh - 32) * DH);
  float sc = isQ ? SCALE : 1.0f;
  float c  = cosb[s * DH + i];
  float sn = sinb[s * DH + i];
  float x1 = bf2f(row[i]);
  float x2 = bf2f(row[i + 64]);
  row[i]      = f2bf((x1 * c - x2 * sn) * sc);
  row[i + 64] = f2bf((x2 * c + x1 * sn) * sc);
}

// ---------------- V transpose: C[s][5120+e] -> VT[kvh][d][s] ----------------
__global__ __launch_bounds__(256) void transpose_v(const unsigned short* __restrict__ Vbuf,
                                                   unsigned short* __restrict__ VT) {
  __shared__ unsigned short t[64][72];
  const int s0 = blockIdx.x * 64, e0 = blockIdx.y * 64;
  const int r = threadIdx.x >> 3, c = (threadIdx.x & 7) * 8;
#pragma unroll
  for (int half = 0; half < 2; ++half) {
    int row = r + half * 32;
    *reinterpret_cast<short8*>(&t[row][c]) =
        *reinterpret_cast<const short8*>(Vbuf + (size_t)(s0 + row) * NQKV + e0 + c);
  }
  __syncthreads();
  const int hh = e0 >> 7, dbase = e0 & 127;
#pragma unroll
  for (int half = 0; half < 2; ++half) {
    int row = r + half * 32;
    short8 o;
#pragma unroll
    for (int j = 0; j < 8; ++j) ((unsigned short*)&o)[j] = t[c + j][row];
    *reinterpret_cast<short8*>(VT + (size_t)hh * (DH * (size_t)S_LEN)
                               + (size_t)(dbase + row) * S_LEN + s0 + c) = o;
  }
}

// ---------------- GQA causal flash attention (round-6, unchanged) ----------------
__global__ __launch_bounds__(256) void attn_fwd(const unsigned short* __restrict__ C,
                                                const unsigned short* __restrict__ VT,
                                                unsigned short* __restrict__ Ob) {
  __shared__ unsigned short KVs[2][8192];   // 16 KB per buffer: K[32][128] swz @0, V^T[128][32] swz @8KB
  __shared__ unsigned short Pl[4][16 * 40];
  const int tid = threadIdx.x, lane = tid & 63, wave = tid >> 6;
  const int kvh = blockIdx.x & 7;
  const int p = blockIdx.x >> 3;
  const int h = kvh * 4 + wave;
  const int fr = lane & 15, fq = lane >> 4;
  const int q0s[2] = { p * 16, (127 - p) * 16 };
  const int tilesA = (p * 16 + 47) >> 5;
  const int tilesB = ((127 - p) * 16 + 47) >> 5;

  const unsigned short* Qbase = C + (size_t)h * DH;
  const unsigned short* Kbase = C + 4096 + (size_t)kvh * DH;
  const unsigned short* Vbase = VT + (size_t)kvh * (DH * (size_t)S_LEN);

  short8 qf[2][4];
#pragma unroll
  for (int s = 0; s < 2; ++s)
#pragma unroll
    for (int dc = 0; dc < 4; ++dc)
      qf[s][dc] = *reinterpret_cast<const short8*>(
          Qbase + (size_t)(q0s[s] + fr) * NQKV + dc * 32 + fq * 8);

  f32x4 o_acc[2][8] = {};
  float mrow[2][4] = {{-1e30f,-1e30f,-1e30f,-1e30f},{-1e30f,-1e30f,-1e30f,-1e30f}};
  float lpart[2][4] = {};

  auto STAGE = [&](int t, int buf) {
    const int kv0 = t * 32;
    char* dst = (char*)&KVs[buf][0];
#pragma unroll
    for (int sh = 0; sh < 2; ++sh) {
      int b = sh * 4096 + tid * 16;
      int krow = b >> 8;
      int kcol = (b & 255) ^ ((krow & 7) << 4);
      __builtin_amdgcn_global_load_lds(
          (const __attribute__((address_space(1))) void*)(Kbase + (size_t)(kv0 + krow) * NQKV + (kcol >> 1)),
          (__attribute__((address_space(3))) void*)(dst + b), 16, 0, 0);
      int vrow = b >> 6;
      int vcol = (b & 63) ^ ((((vrow ^ (vrow >> 2)) & 3)) << 4);
      __builtin_amdgcn_global_load_lds(
          (const __attribute__((address_space(1))) void*)(Vbase + (size_t)vrow * S_LEN + kv0 + (vcol >> 1)),
          (__attribute__((address_space(3))) void*)(dst + 8192 + b), 16, 0, 0);
    }
  };

  int cur = 0;
  STAGE(0, 0);
  asm volatile("s_waitcnt vmcnt(0)" ::: "memory");
  __syncthreads();

  for (int t = 0; t < tilesB; ++t) {
    const int kv0 = t * 32;
    if (t + 1 < tilesB) STAGE(t + 1, cur ^ 1);
    const char* kvb = (const char*)&KVs[cur][0];

#pragma unroll
    for (int s = 0; s < 2; ++s) {
      if (s == 0 && t >= tilesA) continue;
      const int q0 = q0s[s];

      f32x4 sacc[2] = {};
#pragma unroll
      for (int nt = 0; nt < 2; ++nt) {
        const int row = nt * 16 + fr;
#pragma unroll
        for (int dc = 0; dc < 4; ++dc) {
          short8 kf = *reinterpret_cast<const short8*>(
              kvb + row * 256 + ((dc * 64 + fq * 16) ^ ((row & 7) << 4)));
          sacc[nt] = __builtin_amdgcn_mfma_f32_16x16x32_bf16(qf[s][dc], kf, sacc[nt], 0, 0, 0);
        }
      }

      const bool needMask = (kv0 + 32 > q0);
      if (needMask) {
#pragma unroll
        for (int j = 0; j < 4; ++j) {
          int qrow = q0 + fq * 4 + j;
#pragma unroll
          for (int nt = 0; nt < 2; ++nt)
            sacc[nt][j] = ((kv0 + nt*16 + fr) <= qrow) ? sacc[nt][j] : -1e30f;
        }
      }
      bool ok = true;
      float lm[4];
#pragma unroll
      for (int j = 0; j < 4; ++j) {
        lm[j] = fmaxf(sacc[0][j], sacc[1][j]);
        ok = ok && (lm[j] <= mrow[s][j] + 8.f);
      }
      if (!__all(ok)) {
#pragma unroll
        for (int j = 0; j < 4; ++j) {
          float rm = lm[j];
          rm = fmaxf(rm, __shfl_xor(rm, 1));
          rm = fmaxf(rm, __shfl_xor(rm, 2));
          rm = fmaxf(rm, __shfl_xor(rm, 4));
          rm = fmaxf(rm, __shfl_xor(rm, 8));
          float mnew = fmaxf(mrow[s][j], rm);
          float corr = __expf(mrow[s][j] - mnew);
          mrow[s][j] = mnew;
          lpart[s][j] *= corr;
#pragma unroll
          for (int dt = 0; dt < 8; ++dt) o_acc[s][dt][j] *= corr;
        }
      }
#pragma unroll
      for (int j = 0; j < 4; ++j) {
        float p0 = __expf(sacc[0][j] - mrow[s][j]);
        float p1 = __expf(sacc[1][j] - mrow[s][j]);
        lpart[s][j] += p0 + p1;
        unsigned int u;
        asm("v_cvt_pk_bf16_f32 %0, %1, %2" : "=v"(u) : "v"(p0), "v"(p1));
        Pl[wave][(fq*4 + j)*40 + fr]      = (unsigned short)u;
        Pl[wave][(fq*4 + j)*40 + 16 + fr] = (unsigned short)(u >> 16);
      }
      asm volatile("s_waitcnt lgkmcnt(0)" ::: "memory");
      __builtin_amdgcn_sched_barrier(0);

      short8 pa = *reinterpret_cast<const short8*>(&Pl[wave][fr*40 + fq*8]);
#pragma unroll
      for (int dt = 0; dt < 8; ++dt) {
        const int row = dt * 16 + fr;
        short8 bv = *reinterpret_cast<const short8*>(
            kvb + 8192 + row * 64 + ((fq * 16) ^ ((((row ^ (row >> 2)) & 3)) << 4)));
        o_acc[s][dt] = __builtin_amdgcn_mfma_f32_16x16x32_bf16(pa, bv, o_acc[s][dt], 0, 0, 0);
      }
    }

    asm volatile("s_waitcnt vmcnt(0)" ::: "memory");
    __syncthreads();
    cur ^= 1;
  }

#pragma unroll
  for (int s = 0; s < 2; ++s)
#pragma unroll
    for (int j = 0; j < 4; ++j) {
      float l = lpart[s][j];
      l += __shfl_xor(l, 1);
      l += __shfl_xor(l, 2);
      l += __shfl_xor(l, 4);
      l += __shfl_xor(l, 8);
      float inv = 1.f / l;
      size_t r = (size_t)q0s[s] + fq*4 + j;
#pragma unroll
      for (int dt = 0; dt < 8; ++dt)
        Ob[r * QDIM + h * DH + dt*16 + fr] = f2bf(o_acc[s][dt][j] * inv);
    }
}

// ---------------- launch ----------------
extern "C" void kernel_launch(void* const* d_in, const int* in_sizes, int n_in,
                              void* d_out, int out_size, void* d_ws, size_t ws_size,
                              hipStream_t stream) {
  (void)in_sizes; (void)n_in; (void)out_size; (void)ws_size;
  const float* x    = (const float*)d_in[0];
  const float* Wq   = (const float*)d_in[1];
  const float* Wk   = (const float*)d_in[2];
  const float* Wv   = (const float*)d_in[3];
  const float* Wo   = (const float*)d_in[4];
  const float* cosb = (const float*)d_in[5];
  const float* sinb = (const float*)d_in[6];

  char* ws = (char*)d_ws;
  unsigned short* xb    = (unsigned short*)(ws);               // 16.8 MB (dead after QKV gemm)
  unsigned short* Wqkvb = (unsigned short*)(ws + 16777216);    // 50.3 MB [Wq;Wk;Wv]
  unsigned short* Wob   = (unsigned short*)(ws + 67108864);    // 33.6 MB
  unsigned short* Cqkv  = (unsigned short*)(ws + 100663296);   // 25.2 MB [Q|K|V] stride 6144
  unsigned short* VT    = (unsigned short*)(ws + 125829120);   // 4.2 MB
  unsigned short* Ab    = xb;                                  // reuse

  cvt_all<<<49152, 256, 0, stream>>>(x, Wq, Wk, Wv, Wo, xb, Wqkvb, Wob);

  // QKV projection: 256x192 tiles -> 8m x 32n = 256 blocks (CHN=4 n-tiles/XCD)
  gemm8p<2048, 6144, 4096, 256, 192, 1, 4><<<256, 512, 0, stream>>>(xb, Wqkvb, Cqkv);

  rope_fused<<<20480, 256, 0, stream>>>(Cqkv, cosb, sinb);
  transpose_v<<<dim3(32, 16), 256, 0, stream>>>(Cqkv + 5120, VT);

  attn_fwd<<<512, 256, 0, stream>>>(Cqkv, VT, Ab);

  // Output projection: 128x256 tiles -> 16m x 16n = 256 blocks (CHN=2 n-tiles/XCD)
  gemm8p<2048, 4096, 4096, 128, 256, 0, 2><<<256, 512, 0, stream>>>(Ab, Wob, d_out);
}